// Round 20
// baseline (364.639 us; speedup 1.0000x reference)
//
#include <hip/hip_runtime.h>
#include <math.h>

constexpr int NNODES  = 16384;
constexpr int NEDGES  = 131072;
constexpr int NGRAPHS = 16;

typedef short bf16x8 __attribute__((ext_vector_type(8)));
typedef short bf16x4 __attribute__((ext_vector_type(4)));
typedef float f32x4  __attribute__((ext_vector_type(4)));

__device__ __forceinline__ float leaky(float x, float s){ return x >= 0.0f ? x : s * x; }

__device__ __forceinline__ unsigned short f2bf(float f){
  unsigned u = __builtin_bit_cast(unsigned, f);
  u += 0x7FFFu + ((u >> 16) & 1u);          // round-to-nearest-even
  return (unsigned short)(u >> 16);
}
__device__ __forceinline__ float bf2f(unsigned short u){
  unsigned x = (unsigned)u << 16; return __builtin_bit_cast(float, x);
}

__device__ __forceinline__ void gload_lds16(const unsigned short* g, unsigned short* l){
  __builtin_amdgcn_global_load_lds((const __attribute__((address_space(1))) void*)g,
                                   (__attribute__((address_space(3))) void*)l, 16, 0, 0);
}

// ---------------- CSR build (edges fixed across layers; build once) ----------------
__global__ void k_deg(const int* __restrict__ dst, int* __restrict__ deg){
  int e = blockIdx.x * 256 + threadIdx.x;
  if (e < NEDGES) atomicAdd(&deg[dst[e]], 1);
}

__global__ __launch_bounds__(1024) void k_scan(const int* __restrict__ deg,
                                               int* __restrict__ rowptr,
                                               int* __restrict__ cursor){
  __shared__ int sums[1024];
  int t = threadIdx.x;
  int loc[16];
  int s = 0;
  #pragma unroll
  for (int i = 0; i < 16; i++){ loc[i] = deg[t*16 + i]; s += loc[i]; }
  sums[t] = s; __syncthreads();
  for (int off = 1; off < 1024; off <<= 1){
    int v = (t >= off) ? sums[t - off] : 0;
    __syncthreads();
    sums[t] += v;
    __syncthreads();
  }
  int base = (t > 0) ? sums[t-1] : 0;
  #pragma unroll
  for (int i = 0; i < 16; i++){
    rowptr[t*16 + i] = base; cursor[t*16 + i] = base; base += loc[i];
  }
  if (t == 1023) rowptr[NNODES] = base;
}

__global__ void k_scatter(const int* __restrict__ src, const int* __restrict__ dst,
                          int* __restrict__ cursor, int* __restrict__ perm){
  int e = blockIdx.x * 256 + threadIdx.x;
  if (e < NEDGES){ int p = atomicAdd(&cursor[dst[e]], 1); perm[p] = src[e]; }
}

// ---- graph-size counts: LDS histogram per block, one global atomic per (block,graph) ----
__global__ __launch_bounds__(256) void k_counts(const int* __restrict__ gid, float* __restrict__ counts){
  __shared__ int h[NGRAPHS];
  int t = threadIdx.x;
  if (t < NGRAPHS) h[t] = 0;
  __syncthreads();
  int base = blockIdx.x * 1024;
  #pragma unroll
  for (int i = 0; i < 4; i++)
    atomicAdd(&h[gid[base + t + i*256]], 1);
  __syncthreads();
  if (t < NGRAPHS && h[t] > 0) atomicAdd(&counts[t], (float)h[t]);
}

// ---------------- fp32 -> bf16 convert (contiguous) ----------------
__global__ void k_cvt(const float* __restrict__ in, unsigned short* __restrict__ out, int n4){
  int i = blockIdx.x * 256 + threadIdx.x;
  if (i >= n4) return;
  float4 v = ((const float4*)in)[i];
  ushort4 o; o.x = f2bf(v.x); o.y = f2bf(v.y); o.z = f2bf(v.z); o.w = f2bf(v.w);
  ((ushort4*)out)[i] = o;
}

// -------- fp32 [K][NN] -> bf16 transposed [NN][K], both W and RW in one launch --------
__global__ __launch_bounds__(256) void k_cvt_t2(const float* __restrict__ W,
                                                const float* __restrict__ RW,
                                                unsigned short* __restrict__ Wt,
                                                unsigned short* __restrict__ RWt,
                                                int K, int NN){
  __shared__ float tile[32][33];
  const float* src = blockIdx.z ? RW : W;
  unsigned short* dst = blockIdx.z ? RWt : Wt;
  int n0 = blockIdx.x * 32, k0 = blockIdx.y * 32;
  int tx = threadIdx.x & 31, ty = threadIdx.x >> 5;   // 32 x 8
  #pragma unroll
  for (int i = 0; i < 4; i++)
    tile[ty + i*8][tx] = src[(size_t)(k0 + ty + i*8) * NN + n0 + tx];
  __syncthreads();
  #pragma unroll
  for (int i = 0; i < 4; i++)
    dst[(size_t)(n0 + ty + i*8) * K + k0 + tx] = f2bf(tile[tx][ty + i*8]);
}

// ------- fused dual bf16 MFMA GEMM (R18: BK=32, counted-vmcnt, free swizzle) -------
// 128x128 tile, BK=32, double-buffered LDS (32KB -> 5 blocks/CU declared via
// __launch_bounds__(256,5)). Per K-step: issue 4 next-tile global_load_lds,
// s_waitcnt vmcnt(4) (drains only current tile), s_barrier, ds_read+16 MFMA,
// s_barrier. LDS rows 64B; swizzle 16B-slot ^= ((row>>1)&3)<<4 (2-way free).
// W-half epilogue: per-64-col el/er partial dots -> elp/erp (plain stores).
__global__ __launch_bounds__(256, 5) void k_gemm2(const unsigned short* __restrict__ A,
                                               const unsigned short* __restrict__ Wt,
                                               const unsigned short* __restrict__ RWt,
                                               unsigned short* __restrict__ HB,
                                               unsigned short* __restrict__ RB,
                                               const float* __restrict__ al,
                                               const float* __restrict__ ar,
                                               float* __restrict__ elp,
                                               float* __restrict__ erp,
                                               int K, int NN){
  __shared__ unsigned short As[2][128 * 32];
  __shared__ unsigned short Bs[2][128 * 32];
  int t = threadIdx.x;
  int lane = t & 63, w = t >> 6;
  int nx  = gridDim.x;                       // 2*NN/128
  int nwg = nx * gridDim.y;                  // multiple of 8
  int bid = blockIdx.x + blockIdx.y * nx;
  int wg  = (bid & 7) * (nwg >> 3) + (bid >> 3);
  int bx = wg % nx, by = wg / nx;
  int half = nx >> 1;
  bool isW = bx < half;
  const unsigned short* Bt = isW ? Wt : RWt;
  int colB = (isW ? bx : bx - half) * 128;
  int rowA = by * 128;

  int wr = (w >> 1) * 64, wc = (w & 1) * 64;
  int l16 = lane & 15, lhi = lane >> 4;
  f32x4 acc[4][4] = {};

  // staging: 512 chunks of 16B per matrix/tile; thread t -> chunks t and t+256.
  int srow = t >> 2;                                    // 0..63; +64 for chunk t+256
  int skb  = ((t & 3) << 4) ^ (((srow >> 1) & 3) << 4); // bytes; same for srow+64
  const unsigned short* Ap = A  + (size_t)(rowA + srow) * K + (skb >> 1);
  const unsigned short* Bp = Bt + (size_t)(colB + srow) * K + (skb >> 1);
  size_t rstep = (size_t)64 * K;                        // +64 rows

  int nt = K >> 5;
  // prologue: stage tile 0 into buf 0 (4 loads in flight; no drain yet)
  gload_lds16(Ap,         &As[0][t * 8]);
  gload_lds16(Ap + rstep, &As[0][(t + 256) * 8]);
  gload_lds16(Bp,         &Bs[0][t * 8]);
  gload_lds16(Bp + rstep, &Bs[0][(t + 256) * 8]);

  int cur = 0;
  for (int tI = 0; tI < nt; tI++){
    if (tI + 1 < nt){
      int k0n = (tI + 1) << 5;
      gload_lds16(Ap + k0n,         &As[cur ^ 1][t * 8]);
      gload_lds16(Ap + k0n + rstep, &As[cur ^ 1][(t + 256) * 8]);
      gload_lds16(Bp + k0n,         &Bs[cur ^ 1][t * 8]);
      gload_lds16(Bp + k0n + rstep, &Bs[cur ^ 1][(t + 256) * 8]);
      asm volatile("s_waitcnt vmcnt(4)" ::: "memory");
    } else {
      asm volatile("s_waitcnt vmcnt(0)" ::: "memory");
    }
    __builtin_amdgcn_s_barrier();            // all waves drained tile tI's loads
    __builtin_amdgcn_sched_barrier(0);       // rule #18: pin reads below the wait
    int kb = lhi * 16;                       // this lane's 16B k-slot
    bf16x8 af[4], bfr[4];
    #pragma unroll
    for (int mi = 0; mi < 4; mi++){
      int row = wr + mi * 16 + l16;
      int off = row * 64 + (kb ^ (((row >> 1) & 3) << 4));
      af[mi] = *(const bf16x8*)((const char*)As[cur] + off);
    }
    #pragma unroll
    for (int ni = 0; ni < 4; ni++){
      int row = wc + ni * 16 + l16;
      int off = row * 64 + (kb ^ (((row >> 1) & 3) << 4));
      bfr[ni] = *(const bf16x8*)((const char*)Bs[cur] + off);
    }
    #pragma unroll
    for (int mi = 0; mi < 4; mi++)
      #pragma unroll
      for (int ni = 0; ni < 4; ni++)
        acc[mi][ni] = __builtin_amdgcn_mfma_f32_16x16x32_bf16(af[mi], bfr[ni], acc[mi][ni], 0, 0, 0);
    __builtin_amdgcn_s_barrier();
    cur ^= 1;
  }

  unsigned short* C = isW ? HB : RB;
  #pragma unroll
  for (int mi = 0; mi < 4; mi++){
    #pragma unroll
    for (int j = 0; j < 4; j++){
      int r = rowA + wr + mi * 16 + lhi * 4 + j;
      unsigned short* Cp = C + (size_t)r * NN + colB + wc + l16;
      #pragma unroll
      for (int ni = 0; ni < 4; ni++)
        Cp[ni * 16] = f2bf(acc[mi][ni][j]);
    }
  }

  if (isW){
    int G = NN >> 6;                    // 64-col groups across nn
    int g64 = (colB + wc) >> 6;
    float alv[4], arv[4];
    #pragma unroll
    for (int ni = 0; ni < 4; ni++){
      int col = colB + wc + ni * 16 + l16;
      alv[ni] = al[col]; arv[ni] = ar[col];
    }
    #pragma unroll
    for (int mi = 0; mi < 4; mi++){
      #pragma unroll
      for (int j = 0; j < 4; j++){
        float pe = acc[mi][0][j]*alv[0] + acc[mi][1][j]*alv[1]
                 + acc[mi][2][j]*alv[2] + acc[mi][3][j]*alv[3];
        float pr = acc[mi][0][j]*arv[0] + acc[mi][1][j]*arv[1]
                 + acc[mi][2][j]*arv[2] + acc[mi][3][j]*arv[3];
        #pragma unroll
        for (int o = 8; o; o >>= 1){ pe += __shfl_xor(pe, o); pr += __shfl_xor(pr, o); }
        if (l16 == 0){
          int r = rowA + wr + mi * 16 + lhi * 4 + j;
          elp[(size_t)r * G + g64] = pe;
          erp[(size_t)r * G + g64] = pr;
        }
      }
    }
  }
}

// ---- reduce el/er partials: one thread per row; G = nn/64, half per head ----
__global__ void k_elred(const float* __restrict__ elp, const float* __restrict__ erp,
                        float* __restrict__ el, float* __restrict__ er, int G){
  int row = blockIdx.x * 256 + threadIdx.x;
  int half = G >> 1;
  float s0 = 0.f, s1 = 0.f, q0 = 0.f, q1 = 0.f;
  const float* ep = elp + (size_t)row * G;
  const float* rp = erp + (size_t)row * G;
  for (int i = 0; i < half; i++){ s0 += ep[i]; q0 += rp[i]; }
  for (int i = half; i < G; i++){ s1 += ep[i]; q1 += rp[i]; }
  el[row*2] = s0; el[row*2+1] = s1;
  er[row*2] = q0; er[row*2+1] = q1;
}

// ------- attention: one wave per destination node; 4-way edge-unrolled accumulate -------
template<int D>
__global__ __launch_bounds__(256) void k_attn(const unsigned short* __restrict__ HB,
                                              unsigned short* __restrict__ RB,
                                              const float* __restrict__ el,
                                              const float* __restrict__ er,
                                              const int* __restrict__ rowptr,
                                              const int* __restrict__ perm){
  constexpr int ITER = (2*D)/256;
  int wid = threadIdx.x >> 6, lane = threadIdx.x & 63;
  int nb = (blockIdx.x & 7) * (NNODES/4/8) + (blockIdx.x >> 3);   // bijective: 4096 = 8*512
  int n = nb * 4 + wid;
  int r0 = rowptr[n], r1 = rowptr[n+1];
  if (r0 == r1) return;   // no in-edges: output = residual already in RB
  float er0 = er[n*2], er1 = er[n*2+1];
  float mx0 = -1e30f, mx1 = -1e30f;
  for (int e = r0 + lane; e < r1; e += 64){
    int s = perm[e];
    mx0 = fmaxf(mx0, leaky(el[s*2]   + er0, 0.2f));
    mx1 = fmaxf(mx1, leaky(el[s*2+1] + er1, 0.2f));
  }
  #pragma unroll
  for (int o = 32; o; o >>= 1){ mx0 = fmaxf(mx0, __shfl_xor(mx0, o)); mx1 = fmaxf(mx1, __shfl_xor(mx1, o)); }
  float sm0 = 0.0f, sm1 = 0.0f;
  for (int e = r0 + lane; e < r1; e += 64){
    int s = perm[e];
    sm0 += expf(leaky(el[s*2]   + er0, 0.2f) - mx0);
    sm1 += expf(leaky(el[s*2+1] + er1, 0.2f) - mx1);
  }
  #pragma unroll
  for (int o = 32; o; o >>= 1){ sm0 += __shfl_xor(sm0, o); sm1 += __shfl_xor(sm1, o); }
  float inv0 = 1.0f / sm0, inv1 = 1.0f / sm1;
  float acc[ITER][4];
  #pragma unroll
  for (int j = 0; j < ITER; j++)
    #pragma unroll
    for (int i = 0; i < 4; i++) acc[j][i] = 0.0f;
  int e = r0;
  // 4-way unroll: 4 edges' gathers issued together -> latency overlapped
  for (; e + 3 < r1; e += 4){
    int s0 = perm[e], s1 = perm[e+1], s2 = perm[e+2], s3 = perm[e+3];
    float w00 = expf(leaky(el[s0*2]   + er0, 0.2f) - mx0) * inv0;
    float w01 = expf(leaky(el[s0*2+1] + er1, 0.2f) - mx1) * inv1;
    float w10 = expf(leaky(el[s1*2]   + er0, 0.2f) - mx0) * inv0;
    float w11 = expf(leaky(el[s1*2+1] + er1, 0.2f) - mx1) * inv1;
    float w20 = expf(leaky(el[s2*2]   + er0, 0.2f) - mx0) * inv0;
    float w21 = expf(leaky(el[s2*2+1] + er1, 0.2f) - mx1) * inv1;
    float w30 = expf(leaky(el[s3*2]   + er0, 0.2f) - mx0) * inv0;
    float w31 = expf(leaky(el[s3*2+1] + er1, 0.2f) - mx1) * inv1;
    const unsigned short* h0 = HB + (size_t)s0 * (2*D);
    const unsigned short* h1 = HB + (size_t)s1 * (2*D);
    const unsigned short* h2 = HB + (size_t)s2 * (2*D);
    const unsigned short* h3 = HB + (size_t)s3 * (2*D);
    #pragma unroll
    for (int j = 0; j < ITER; j++){
      int base = j*256 + lane*4;
      bf16x4 v0 = *(const bf16x4*)(h0 + base);
      bf16x4 v1 = *(const bf16x4*)(h1 + base);
      bf16x4 v2 = *(const bf16x4*)(h2 + base);
      bf16x4 v3 = *(const bf16x4*)(h3 + base);
      float a0 = (base < D) ? w00 : w01;
      float a1 = (base < D) ? w10 : w11;
      float a2 = (base < D) ? w20 : w21;
      float a3 = (base < D) ? w30 : w31;
      #pragma unroll
      for (int i = 0; i < 4; i++)
        acc[j][i] += a0 * bf2f((unsigned short)v0[i]) + a1 * bf2f((unsigned short)v1[i])
                   + a2 * bf2f((unsigned short)v2[i]) + a3 * bf2f((unsigned short)v3[i]);
    }
  }
  for (; e < r1; ++e){
    int s = perm[e];
    float a0 = expf(leaky(el[s*2]   + er0, 0.2f) - mx0) * inv0;
    float a1 = expf(leaky(el[s*2+1] + er1, 0.2f) - mx1) * inv1;
    const unsigned short* hrow = HB + (size_t)s * (2*D);
    #pragma unroll
    for (int j = 0; j < ITER; j++){
      int base = j*256 + lane*4;
      bf16x4 v = *(const bf16x4*)(hrow + base);
      float a = (base < D) ? a0 : a1;
      #pragma unroll
      for (int i = 0; i < 4; i++)
        acc[j][i] += a * bf2f((unsigned short)v[i]);
    }
  }
  unsigned short* rrow = RB + (size_t)n * (2*D);
  #pragma unroll
  for (int j = 0; j < ITER; j++){
    int base = j*256 + lane*4;
    bf16x4 r = *(bf16x4*)(rrow + base);
    ushort4 o;
    o.x = f2bf(bf2f((unsigned short)r[0]) + acc[j][0]);
    o.y = f2bf(bf2f((unsigned short)r[1]) + acc[j][1]);
    o.z = f2bf(bf2f((unsigned short)r[2]) + acc[j][2]);
    o.w = f2bf(bf2f((unsigned short)r[3]) + acc[j][3]);
    *(ushort4*)(rrow + base) = o;
  }
}

// ------- GraphNorm stats (bf16 in): grid (NNODES/128, nn/256); lane owns 4 cols -------
__global__ __launch_bounds__(256) void k_stats(const unsigned short* __restrict__ R, int nn,
                                               float* __restrict__ gsum, float* __restrict__ gsq){
  int t = threadIdx.x, lane = t & 63, w = t >> 6;
  int c = blockIdx.y * 256 + lane * 4;
  const unsigned short* base = R + (size_t)(blockIdx.x * 128 + w) * nn + c;
  float4 s = make_float4(0,0,0,0), q = make_float4(0,0,0,0);
  #pragma unroll 4
  for (int i = 0; i < 32; i++){
    bf16x4 bv = *(const bf16x4*)(base + (size_t)(i * 4) * nn);
    float vx = bf2f((unsigned short)bv[0]), vy = bf2f((unsigned short)bv[1]);
    float vz = bf2f((unsigned short)bv[2]), vw = bf2f((unsigned short)bv[3]);
    s.x += vx; s.y += vy; s.z += vz; s.w += vw;
    q.x += vx*vx; q.y += vy*vy; q.z += vz*vz; q.w += vw*vw;
  }
  __shared__ float4 rs[256], rq[256];
  rs[t] = s; rq[t] = q; __syncthreads();
  if (t < 64){
    float4 a = rs[t], b = rs[t+64], c2 = rs[t+128], d2 = rs[t+192];
    float4 e = rq[t], f = rq[t+64], g2 = rq[t+128], h2 = rq[t+192];
    int cc = blockIdx.y * 256 + t * 4;
    atomicAdd(&gsum[cc+0], a.x+b.x+c2.x+d2.x);
    atomicAdd(&gsum[cc+1], a.y+b.y+c2.y+d2.y);
    atomicAdd(&gsum[cc+2], a.z+b.z+c2.z+d2.z);
    atomicAdd(&gsum[cc+3], a.w+b.w+c2.w+d2.w);
    atomicAdd(&gsq [cc+0], e.x+f.x+g2.x+h2.x);
    atomicAdd(&gsq [cc+1], e.y+f.y+g2.y+h2.y);
    atomicAdd(&gsq [cc+2], e.z+f.z+g2.z+h2.z);
    atomicAdd(&gsq [cc+3], e.w+f.w+g2.w+h2.w);
  }
}

// -- norm apply + leaky + head-mean pool (bf16 in) with INLINE stats finalize --
// grid (NNODES/128, nn/256); params are d-length; column c -> channel c & (d-1).
__global__ __launch_bounds__(256) void k_norm_pool(const unsigned short* __restrict__ R,
                                                   unsigned short* __restrict__ Xn, // bf16 next-layer input (or null)
                                                   const float* __restrict__ gsum,
                                                   const float* __restrict__ gsq,
                                                   const float* __restrict__ gamma,
                                                   const float* __restrict__ beta,
                                                   const float* __restrict__ alpha,
                                                   float* __restrict__ pool, int d, int loff){
  int t = threadIdx.x, lane = t & 63, w = t >> 6;
  int c = blockIdx.y * 256 + lane * 4;
  int cm = c & (d - 1);                    // channel index (d-periodic), 4-aligned
  int nodeb = blockIdx.x * 128;
  int g = blockIdx.x >> 3;                 // 8 row-blocks per graph (1024 nodes/graph)
  int nn = 2 * d;
  const float Minv = 1.0f / (2.0f * (float)NNODES);
  float4 gg = *(const float4*)(gamma + cm);
  float4 bb = *(const float4*)(beta + cm);
  float4 aa = *(const float4*)(alpha + cm);
  float mmv[4], rrv[4];
  #pragma unroll
  for (int i = 0; i < 4; i++){
    float m = (gsum[cm+i] + gsum[cm+i+d]) * Minv;
    float q = (gsq [cm+i] + gsq [cm+i+d]) * Minv;
    float a = (i==0)?aa.x:(i==1)?aa.y:(i==2)?aa.z:aa.w;
    float var = q - a * m * m * (2.0f - a);
    mmv[i] = m; rrv[i] = rsqrtf(var + 1e-5f);
  }
  float am0 = aa.x*mmv[0], am1 = aa.y*mmv[1], am2 = aa.z*mmv[2], am3 = aa.w*mmv[3];
  const unsigned short* base = R + (size_t)(nodeb + w) * nn + c;
  unsigned short* xb = Xn ? (Xn + (size_t)(nodeb + w) * nn + c) : nullptr;
  float4 accp = make_float4(0,0,0,0);
  #pragma unroll 4
  for (int i = 0; i < 32; i++){
    bf16x4 bv = *(const bf16x4*)(base + (size_t)(i * 4) * nn);
    float vx = bf2f((unsigned short)bv[0]), vy = bf2f((unsigned short)bv[1]);
    float vz = bf2f((unsigned short)bv[2]), vw = bf2f((unsigned short)bv[3]);
    float y0 = gg.x*(vx-am0)*rrv[0] + bb.x; y0 = y0 >= 0.f ? y0 : 0.01f*y0;
    float y1 = gg.y*(vy-am1)*rrv[1] + bb.y; y1 = y1 >= 0.f ? y1 : 0.01f*y1;
    float y2 = gg.z*(vz-am2)*rrv[2] + bb.z; y2 = y2 >= 0.f ? y2 : 0.01f*y2;
    float y3 = gg.w*(vw-am3)*rrv[3] + bb.w; y3 = y3 >= 0.f ? y3 : 0.01f*y3;
    if (xb){
      ushort4 o; o.x = f2bf(y0); o.y = f2bf(y1); o.z = f2bf(y2); o.w = f2bf(y3);
      *(ushort4*)(xb + (size_t)(i * 4) * nn) = o;
    }
    accp.x += y0; accp.y += y1; accp.z += y2; accp.w += y3;
  }
  __shared__ float4 red[256];
  red[t] = accp; __syncthreads();
  if (t < 64){
    float4 a = red[t], b = red[t+64], c2 = red[t+128], d2 = red[t+192];
    int cc = blockIdx.y * 256 + t * 4;
    float* pb = pool + g * 896 + loff;
    atomicAdd(&pb[(cc+0) & (d-1)], 0.5f*(a.x+b.x+c2.x+d2.x));
    atomicAdd(&pb[(cc+1) & (d-1)], 0.5f*(a.y+b.y+c2.y+d2.y));
    atomicAdd(&pb[(cc+2) & (d-1)], 0.5f*(a.z+b.z+c2.z+d2.z));
    atomicAdd(&pb[(cc+3) & (d-1)], 0.5f*(a.w+b.w+c2.w+d2.w));
  }
}

__global__ void k_final(const float* __restrict__ pool, const float* __restrict__ counts,
                        float* __restrict__ out){
  int idx = blockIdx.x * 256 + threadIdx.x;
  if (idx >= NGRAPHS * 896) return;
  int g = idx / 896;
  float v = pool[idx] / counts[g];
  out[idx] = v >= 0.0f ? v : 0.01f * v;
}

// ---------------------------------------------------------------------------------------
extern "C" void kernel_launch(void* const* d_in, const int* in_sizes, int n_in,
                              void* d_out, int out_size, void* d_ws, size_t ws_size,
                              hipStream_t stream){
  const float* x0 = (const float*)d_in[0];
  const float *W[3], *AL[3], *AR[3], *RW[3], *GA[3], *BE[3], *ALP[3];
  for (int l = 0; l < 3; l++){
    const int b = 1 + l*7;
    W[l]  = (const float*)d_in[b+0];
    AL[l] = (const float*)d_in[b+1];
    AR[l] = (const float*)d_in[b+2];
    RW[l] = (const float*)d_in[b+3];
    GA[l] = (const float*)d_in[b+4];
    BE[l] = (const float*)d_in[b+5];
    ALP[l]= (const float*)d_in[b+6];
  }
  const int* esrc = (const int*)d_in[22];
  const int* edst = (const int*)d_in[23];
  const int* gid  = (const int*)d_in[24];
  float* out = (float*)d_out;

  char* p = (char*)d_ws;
  auto carve = [&](size_t bytes)->void*{
    void* r = (void*)p; p += (bytes + 255) & ~(size_t)255; return r;
  };
  unsigned short* HB = (unsigned short*)carve((size_t)NNODES * 1024 * 2);  // h bf16 [N, 2d]
  unsigned short* RB = (unsigned short*)carve((size_t)NNODES * 1024 * 2);  // r/out bf16 [N, 2d]
  unsigned short* X0b = (unsigned short*)carve((size_t)NNODES * 128 * 2);  // bf16 layer-0 input
  unsigned short* XA  = (unsigned short*)carve((size_t)NNODES * 256 * 2);  // bf16 y0
  unsigned short* XB  = (unsigned short*)carve((size_t)NNODES * 512 * 2);  // bf16 y1
  unsigned short* Wt  = (unsigned short*)carve((size_t)1024 * 512 * 2);    // bf16 W^T (max)
  unsigned short* RWt = (unsigned short*)carve((size_t)1024 * 512 * 2);    // bf16 resW^T (max)
  float* el     = (float*)carve((size_t)NNODES * 2 * 4);
  float* er     = (float*)carve((size_t)NNODES * 2 * 4);
  float* elp    = (float*)carve((size_t)NNODES * 16 * 4);    // el partials (G<=16)
  float* erp    = (float*)carve((size_t)NNODES * 16 * 4);    // er partials
  int*   deg    = (int*)  carve((size_t)NNODES * 4);
  int*   rowptr = (int*)  carve((size_t)(NNODES + 1) * 4);
  int*   cursor = (int*)  carve((size_t)NNODES * 4);
  int*   perm   = (int*)  carve((size_t)NEDGES * 4);
  float* stats  = (float*)carve(3 * 2048 * 4);               // per-layer gsum|gsq arenas
  float* pool   = (float*)carve((size_t)NGRAPHS * 896 * 4);
  float* countsF= (float*)carve((size_t)NGRAPHS * 4);
  (void)ws_size; (void)in_sizes; (void)n_in; (void)out_size;

  hipMemsetAsync(deg, 0, NNODES * 4, stream);
  hipMemsetAsync(pool, 0, NGRAPHS * 896 * 4, stream);
  hipMemsetAsync(countsF, 0, NGRAPHS * 4, stream);
  hipMemsetAsync(stats, 0, 3 * 2048 * 4, stream);

  k_deg    <<<NEDGES/256, 256, 0, stream>>>(edst, deg);
  k_scan   <<<1, 1024, 0, stream>>>(deg, rowptr, cursor);
  k_scatter<<<NEDGES/256, 256, 0, stream>>>(esrc, edst, cursor, perm);
  k_counts <<<NNODES/1024, 256, 0, stream>>>(gid, countsF);
  k_cvt    <<<(NNODES*128/4 + 255)/256, 256, 0, stream>>>(x0, X0b, NNODES*128/4);

  const unsigned short* xin = X0b;
  int loff = 0;
  const int dims[3] = {128, 256, 512};
  for (int l = 0; l < 3; l++){
    int d = dims[l], nn = 2*d;
    float* gsum = stats + l * 2048;
    float* gsq  = gsum + 1024;
    dim3 gt(nn/32, d/32, 2);
    k_cvt_t2<<<gt, 256, 0, stream>>>(W[l], RW[l], Wt, RWt, d, nn);
    dim3 gg(2*nn/128, NNODES/128);
    k_gemm2<<<gg, 256, 0, stream>>>(xin, Wt, RWt, HB, RB, AL[l], AR[l], elp, erp, d, nn);
    k_elred<<<NNODES/256, 256, 0, stream>>>(elp, erp, el, er, nn >> 6);
    if (d == 128){
      k_attn<128><<<NNODES/4, 256, 0, stream>>>(HB, RB, el, er, rowptr, perm);
    } else if (d == 256){
      k_attn<256><<<NNODES/4, 256, 0, stream>>>(HB, RB, el, er, rowptr, perm);
    } else {
      k_attn<512><<<NNODES/4, 256, 0, stream>>>(HB, RB, el, er, rowptr, perm);
    }
    dim3 gs(NNODES/128, nn/256);
    k_stats   <<<gs, 256, 0, stream>>>(RB, nn, gsum, gsq);
    unsigned short* xn = (l == 0) ? XA : (l == 1) ? XB : nullptr;
    k_norm_pool<<<gs, 256, 0, stream>>>(RB, xn, gsum, gsq, GA[l], BE[l], ALP[l], pool, d, loff);
    xin = xn; loff += d;
  }
  k_final<<<(NGRAPHS*896 + 255)/256, 256, 0, stream>>>(pool, countsF, out);
}

// Round 21
// 335.910 us; speedup vs baseline: 1.0855x; 1.0855x over previous
//
#include <hip/hip_runtime.h>
#include <math.h>

constexpr int NNODES  = 16384;
constexpr int NEDGES  = 131072;
constexpr int NGRAPHS = 16;

typedef short bf16x8 __attribute__((ext_vector_type(8)));
typedef short bf16x4 __attribute__((ext_vector_type(4)));
typedef float f32x4  __attribute__((ext_vector_type(4)));

__device__ __forceinline__ float leaky(float x, float s){ return x >= 0.0f ? x : s * x; }

__device__ __forceinline__ unsigned short f2bf(float f){
  unsigned u = __builtin_bit_cast(unsigned, f);
  u += 0x7FFFu + ((u >> 16) & 1u);          // round-to-nearest-even
  return (unsigned short)(u >> 16);
}
__device__ __forceinline__ float bf2f(unsigned short u){
  unsigned x = (unsigned)u << 16; return __builtin_bit_cast(float, x);
}

__device__ __forceinline__ void gload_lds16(const unsigned short* g, unsigned short* l){
  __builtin_amdgcn_global_load_lds((const __attribute__((address_space(1))) void*)g,
                                   (__attribute__((address_space(3))) void*)l, 16, 0, 0);
}

// ---------------- CSR build (edges fixed across layers; build once) ----------------
__global__ void k_deg(const int* __restrict__ dst, int* __restrict__ deg){
  int e = blockIdx.x * 256 + threadIdx.x;
  if (e < NEDGES) atomicAdd(&deg[dst[e]], 1);
}

__global__ __launch_bounds__(1024) void k_scan(const int* __restrict__ deg,
                                               int* __restrict__ rowptr,
                                               int* __restrict__ cursor){
  __shared__ int sums[1024];
  int t = threadIdx.x;
  int loc[16];
  int s = 0;
  #pragma unroll
  for (int i = 0; i < 16; i++){ loc[i] = deg[t*16 + i]; s += loc[i]; }
  sums[t] = s; __syncthreads();
  for (int off = 1; off < 1024; off <<= 1){
    int v = (t >= off) ? sums[t - off] : 0;
    __syncthreads();
    sums[t] += v;
    __syncthreads();
  }
  int base = (t > 0) ? sums[t-1] : 0;
  #pragma unroll
  for (int i = 0; i < 16; i++){
    rowptr[t*16 + i] = base; cursor[t*16 + i] = base; base += loc[i];
  }
  if (t == 1023) rowptr[NNODES] = base;
}

__global__ void k_scatter(const int* __restrict__ src, const int* __restrict__ dst,
                          int* __restrict__ cursor, int* __restrict__ perm){
  int e = blockIdx.x * 256 + threadIdx.x;
  if (e < NEDGES){ int p = atomicAdd(&cursor[dst[e]], 1); perm[p] = src[e]; }
}

// ---- graph-size counts: LDS histogram per block, one global atomic per (block,graph) ----
__global__ __launch_bounds__(256) void k_counts(const int* __restrict__ gid, float* __restrict__ counts){
  __shared__ int h[NGRAPHS];
  int t = threadIdx.x;
  if (t < NGRAPHS) h[t] = 0;
  __syncthreads();
  int base = blockIdx.x * 1024;
  #pragma unroll
  for (int i = 0; i < 4; i++)
    atomicAdd(&h[gid[base + t + i*256]], 1);
  __syncthreads();
  if (t < NGRAPHS && h[t] > 0) atomicAdd(&counts[t], (float)h[t]);
}

// ---------------- fp32 -> bf16 convert (contiguous) ----------------
__global__ void k_cvt(const float* __restrict__ in, unsigned short* __restrict__ out, int n4){
  int i = blockIdx.x * 256 + threadIdx.x;
  if (i >= n4) return;
  float4 v = ((const float4*)in)[i];
  ushort4 o; o.x = f2bf(v.x); o.y = f2bf(v.y); o.z = f2bf(v.z); o.w = f2bf(v.w);
  ((ushort4*)out)[i] = o;
}

// -------- fp32 [K][NN] -> bf16 transposed [NN][K], both W and RW in one launch --------
__global__ __launch_bounds__(256) void k_cvt_t2(const float* __restrict__ W,
                                                const float* __restrict__ RW,
                                                unsigned short* __restrict__ Wt,
                                                unsigned short* __restrict__ RWt,
                                                int K, int NN){
  __shared__ float tile[32][33];
  const float* src = blockIdx.z ? RW : W;
  unsigned short* dst = blockIdx.z ? RWt : Wt;
  int n0 = blockIdx.x * 32, k0 = blockIdx.y * 32;
  int tx = threadIdx.x & 31, ty = threadIdx.x >> 5;   // 32 x 8
  #pragma unroll
  for (int i = 0; i < 4; i++)
    tile[ty + i*8][tx] = src[(size_t)(k0 + ty + i*8) * NN + n0 + tx];
  __syncthreads();
  #pragma unroll
  for (int i = 0; i < 4; i++)
    dst[(size_t)(n0 + ty + i*8) * K + k0 + tx] = f2bf(tile[tx][ty + i*8]);
}

// ------- fused dual bf16 MFMA GEMM (R18: BK=32, counted-vmcnt, free swizzle) -------
// 128x128 tile, BK=32, double-buffered LDS (32KB). NO min-waves launch_bounds
// (R20 showed forcing 5 waves/EU spills acc to scratch: VGPR 72->48, +20us).
// Per K-step: issue 4 next-tile global_load_lds, s_waitcnt vmcnt(4), s_barrier,
// ds_read+16 MFMA, s_barrier. LDS rows 64B; swizzle 16B-slot ^= ((row>>1)&3)<<4.
// W-half epilogue: per-64-col el/er partial dots -> elp/erp (plain stores).
__global__ __launch_bounds__(256) void k_gemm2(const unsigned short* __restrict__ A,
                                               const unsigned short* __restrict__ Wt,
                                               const unsigned short* __restrict__ RWt,
                                               unsigned short* __restrict__ HB,
                                               unsigned short* __restrict__ RB,
                                               const float* __restrict__ al,
                                               const float* __restrict__ ar,
                                               float* __restrict__ elp,
                                               float* __restrict__ erp,
                                               int K, int NN){
  __shared__ unsigned short As[2][128 * 32];
  __shared__ unsigned short Bs[2][128 * 32];
  int t = threadIdx.x;
  int lane = t & 63, w = t >> 6;
  int nx  = gridDim.x;                       // 2*NN/128
  int nwg = nx * gridDim.y;                  // multiple of 8
  int bid = blockIdx.x + blockIdx.y * nx;
  int wg  = (bid & 7) * (nwg >> 3) + (bid >> 3);
  int bx = wg % nx, by = wg / nx;
  int half = nx >> 1;
  bool isW = bx < half;
  const unsigned short* Bt = isW ? Wt : RWt;
  int colB = (isW ? bx : bx - half) * 128;
  int rowA = by * 128;

  int wr = (w >> 1) * 64, wc = (w & 1) * 64;
  int l16 = lane & 15, lhi = lane >> 4;
  f32x4 acc[4][4] = {};

  // staging: 512 chunks of 16B per matrix/tile; thread t -> chunks t and t+256.
  int srow = t >> 2;                                    // 0..63; +64 for chunk t+256
  int skb  = ((t & 3) << 4) ^ (((srow >> 1) & 3) << 4); // bytes; same for srow+64
  const unsigned short* Ap = A  + (size_t)(rowA + srow) * K + (skb >> 1);
  const unsigned short* Bp = Bt + (size_t)(colB + srow) * K + (skb >> 1);
  size_t rstep = (size_t)64 * K;                        // +64 rows

  int nt = K >> 5;
  // prologue: stage tile 0 into buf 0 (4 loads in flight; no drain yet)
  gload_lds16(Ap,         &As[0][t * 8]);
  gload_lds16(Ap + rstep, &As[0][(t + 256) * 8]);
  gload_lds16(Bp,         &Bs[0][t * 8]);
  gload_lds16(Bp + rstep, &Bs[0][(t + 256) * 8]);

  int cur = 0;
  for (int tI = 0; tI < nt; tI++){
    if (tI + 1 < nt){
      int k0n = (tI + 1) << 5;
      gload_lds16(Ap + k0n,         &As[cur ^ 1][t * 8]);
      gload_lds16(Ap + k0n + rstep, &As[cur ^ 1][(t + 256) * 8]);
      gload_lds16(Bp + k0n,         &Bs[cur ^ 1][t * 8]);
      gload_lds16(Bp + k0n + rstep, &Bs[cur ^ 1][(t + 256) * 8]);
      asm volatile("s_waitcnt vmcnt(4)" ::: "memory");
    } else {
      asm volatile("s_waitcnt vmcnt(0)" ::: "memory");
    }
    __builtin_amdgcn_s_barrier();            // all waves drained tile tI's loads
    __builtin_amdgcn_sched_barrier(0);       // rule #18: pin reads below the wait
    int kb = lhi * 16;                       // this lane's 16B k-slot
    bf16x8 af[4], bfr[4];
    #pragma unroll
    for (int mi = 0; mi < 4; mi++){
      int row = wr + mi * 16 + l16;
      int off = row * 64 + (kb ^ (((row >> 1) & 3) << 4));
      af[mi] = *(const bf16x8*)((const char*)As[cur] + off);
    }
    #pragma unroll
    for (int ni = 0; ni < 4; ni++){
      int row = wc + ni * 16 + l16;
      int off = row * 64 + (kb ^ (((row >> 1) & 3) << 4));
      bfr[ni] = *(const bf16x8*)((const char*)Bs[cur] + off);
    }
    #pragma unroll
    for (int mi = 0; mi < 4; mi++)
      #pragma unroll
      for (int ni = 0; ni < 4; ni++)
        acc[mi][ni] = __builtin_amdgcn_mfma_f32_16x16x32_bf16(af[mi], bfr[ni], acc[mi][ni], 0, 0, 0);
    __builtin_amdgcn_s_barrier();
    cur ^= 1;
  }

  unsigned short* C = isW ? HB : RB;
  #pragma unroll
  for (int mi = 0; mi < 4; mi++){
    #pragma unroll
    for (int j = 0; j < 4; j++){
      int r = rowA + wr + mi * 16 + lhi * 4 + j;
      unsigned short* Cp = C + (size_t)r * NN + colB + wc + l16;
      #pragma unroll
      for (int ni = 0; ni < 4; ni++)
        Cp[ni * 16] = f2bf(acc[mi][ni][j]);
    }
  }

  if (isW){
    int G = NN >> 6;                    // 64-col groups across nn
    int g64 = (colB + wc) >> 6;
    float alv[4], arv[4];
    #pragma unroll
    for (int ni = 0; ni < 4; ni++){
      int col = colB + wc + ni * 16 + l16;
      alv[ni] = al[col]; arv[ni] = ar[col];
    }
    #pragma unroll
    for (int mi = 0; mi < 4; mi++){
      #pragma unroll
      for (int j = 0; j < 4; j++){
        float pe = acc[mi][0][j]*alv[0] + acc[mi][1][j]*alv[1]
                 + acc[mi][2][j]*alv[2] + acc[mi][3][j]*alv[3];
        float pr = acc[mi][0][j]*arv[0] + acc[mi][1][j]*arv[1]
                 + acc[mi][2][j]*arv[2] + acc[mi][3][j]*arv[3];
        #pragma unroll
        for (int o = 8; o; o >>= 1){ pe += __shfl_xor(pe, o); pr += __shfl_xor(pr, o); }
        if (l16 == 0){
          int r = rowA + wr + mi * 16 + lhi * 4 + j;
          elp[(size_t)r * G + g64] = pe;
          erp[(size_t)r * G + g64] = pr;
        }
      }
    }
  }
}

// ---- reduce el/er partials: one thread per row; G = nn/64, half per head ----
__global__ void k_elred(const float* __restrict__ elp, const float* __restrict__ erp,
                        float* __restrict__ el, float* __restrict__ er, int G){
  int row = blockIdx.x * 256 + threadIdx.x;
  int half = G >> 1;
  float s0 = 0.f, s1 = 0.f, q0 = 0.f, q1 = 0.f;
  const float* ep = elp + (size_t)row * G;
  const float* rp = erp + (size_t)row * G;
  for (int i = 0; i < half; i++){ s0 += ep[i]; q0 += rp[i]; }
  for (int i = half; i < G; i++){ s1 += ep[i]; q1 += rp[i]; }
  el[row*2] = s0; el[row*2+1] = s1;
  er[row*2] = q0; er[row*2+1] = q1;
}

// ------- attention: one wave per destination node; 4-way edge-unrolled accumulate -------
template<int D>
__global__ __launch_bounds__(256) void k_attn(const unsigned short* __restrict__ HB,
                                              unsigned short* __restrict__ RB,
                                              const float* __restrict__ el,
                                              const float* __restrict__ er,
                                              const int* __restrict__ rowptr,
                                              const int* __restrict__ perm){
  constexpr int ITER = (2*D)/256;
  int wid = threadIdx.x >> 6, lane = threadIdx.x & 63;
  int nb = (blockIdx.x & 7) * (NNODES/4/8) + (blockIdx.x >> 3);   // bijective: 4096 = 8*512
  int n = nb * 4 + wid;
  int r0 = rowptr[n], r1 = rowptr[n+1];
  if (r0 == r1) return;   // no in-edges: output = residual already in RB
  float er0 = er[n*2], er1 = er[n*2+1];
  float mx0 = -1e30f, mx1 = -1e30f;
  for (int e = r0 + lane; e < r1; e += 64){
    int s = perm[e];
    mx0 = fmaxf(mx0, leaky(el[s*2]   + er0, 0.2f));
    mx1 = fmaxf(mx1, leaky(el[s*2+1] + er1, 0.2f));
  }
  #pragma unroll
  for (int o = 32; o; o >>= 1){ mx0 = fmaxf(mx0, __shfl_xor(mx0, o)); mx1 = fmaxf(mx1, __shfl_xor(mx1, o)); }
  float sm0 = 0.0f, sm1 = 0.0f;
  for (int e = r0 + lane; e < r1; e += 64){
    int s = perm[e];
    sm0 += expf(leaky(el[s*2]   + er0, 0.2f) - mx0);
    sm1 += expf(leaky(el[s*2+1] + er1, 0.2f) - mx1);
  }
  #pragma unroll
  for (int o = 32; o; o >>= 1){ sm0 += __shfl_xor(sm0, o); sm1 += __shfl_xor(sm1, o); }
  float inv0 = 1.0f / sm0, inv1 = 1.0f / sm1;
  float acc[ITER][4];
  #pragma unroll
  for (int j = 0; j < ITER; j++)
    #pragma unroll
    for (int i = 0; i < 4; i++) acc[j][i] = 0.0f;
  int e = r0;
  // 4-way unroll: 4 edges' gathers issued together -> latency overlapped
  for (; e + 3 < r1; e += 4){
    int s0 = perm[e], s1 = perm[e+1], s2 = perm[e+2], s3 = perm[e+3];
    float w00 = expf(leaky(el[s0*2]   + er0, 0.2f) - mx0) * inv0;
    float w01 = expf(leaky(el[s0*2+1] + er1, 0.2f) - mx1) * inv1;
    float w10 = expf(leaky(el[s1*2]   + er0, 0.2f) - mx0) * inv0;
    float w11 = expf(leaky(el[s1*2+1] + er1, 0.2f) - mx1) * inv1;
    float w20 = expf(leaky(el[s2*2]   + er0, 0.2f) - mx0) * inv0;
    float w21 = expf(leaky(el[s2*2+1] + er1, 0.2f) - mx1) * inv1;
    float w30 = expf(leaky(el[s3*2]   + er0, 0.2f) - mx0) * inv0;
    float w31 = expf(leaky(el[s3*2+1] + er1, 0.2f) - mx1) * inv1;
    const unsigned short* h0 = HB + (size_t)s0 * (2*D);
    const unsigned short* h1 = HB + (size_t)s1 * (2*D);
    const unsigned short* h2 = HB + (size_t)s2 * (2*D);
    const unsigned short* h3 = HB + (size_t)s3 * (2*D);
    #pragma unroll
    for (int j = 0; j < ITER; j++){
      int base = j*256 + lane*4;
      bf16x4 v0 = *(const bf16x4*)(h0 + base);
      bf16x4 v1 = *(const bf16x4*)(h1 + base);
      bf16x4 v2 = *(const bf16x4*)(h2 + base);
      bf16x4 v3 = *(const bf16x4*)(h3 + base);
      float a0 = (base < D) ? w00 : w01;
      float a1 = (base < D) ? w10 : w11;
      float a2 = (base < D) ? w20 : w21;
      float a3 = (base < D) ? w30 : w31;
      #pragma unroll
      for (int i = 0; i < 4; i++)
        acc[j][i] += a0 * bf2f((unsigned short)v0[i]) + a1 * bf2f((unsigned short)v1[i])
                   + a2 * bf2f((unsigned short)v2[i]) + a3 * bf2f((unsigned short)v3[i]);
    }
  }
  for (; e < r1; ++e){
    int s = perm[e];
    float a0 = expf(leaky(el[s*2]   + er0, 0.2f) - mx0) * inv0;
    float a1 = expf(leaky(el[s*2+1] + er1, 0.2f) - mx1) * inv1;
    const unsigned short* hrow = HB + (size_t)s * (2*D);
    #pragma unroll
    for (int j = 0; j < ITER; j++){
      int base = j*256 + lane*4;
      bf16x4 v = *(const bf16x4*)(hrow + base);
      float a = (base < D) ? a0 : a1;
      #pragma unroll
      for (int i = 0; i < 4; i++)
        acc[j][i] += a * bf2f((unsigned short)v[i]);
    }
  }
  unsigned short* rrow = RB + (size_t)n * (2*D);
  #pragma unroll
  for (int j = 0; j < ITER; j++){
    int base = j*256 + lane*4;
    bf16x4 r = *(bf16x4*)(rrow + base);
    ushort4 o;
    o.x = f2bf(bf2f((unsigned short)r[0]) + acc[j][0]);
    o.y = f2bf(bf2f((unsigned short)r[1]) + acc[j][1]);
    o.z = f2bf(bf2f((unsigned short)r[2]) + acc[j][2]);
    o.w = f2bf(bf2f((unsigned short)r[3]) + acc[j][3]);
    *(ushort4*)(rrow + base) = o;
  }
}

// ------- GraphNorm stats (bf16 in): grid (NNODES/128, nn/256); lane owns 4 cols -------
__global__ __launch_bounds__(256) void k_stats(const unsigned short* __restrict__ R, int nn,
                                               float* __restrict__ gsum, float* __restrict__ gsq){
  int t = threadIdx.x, lane = t & 63, w = t >> 6;
  int c = blockIdx.y * 256 + lane * 4;
  const unsigned short* base = R + (size_t)(blockIdx.x * 128 + w) * nn + c;
  float4 s = make_float4(0,0,0,0), q = make_float4(0,0,0,0);
  #pragma unroll 4
  for (int i = 0; i < 32; i++){
    bf16x4 bv = *(const bf16x4*)(base + (size_t)(i * 4) * nn);
    float vx = bf2f((unsigned short)bv[0]), vy = bf2f((unsigned short)bv[1]);
    float vz = bf2f((unsigned short)bv[2]), vw = bf2f((unsigned short)bv[3]);
    s.x += vx; s.y += vy; s.z += vz; s.w += vw;
    q.x += vx*vx; q.y += vy*vy; q.z += vz*vz; q.w += vw*vw;
  }
  __shared__ float4 rs[256], rq[256];
  rs[t] = s; rq[t] = q; __syncthreads();
  if (t < 64){
    float4 a = rs[t], b = rs[t+64], c2 = rs[t+128], d2 = rs[t+192];
    float4 e = rq[t], f = rq[t+64], g2 = rq[t+128], h2 = rq[t+192];
    int cc = blockIdx.y * 256 + t * 4;
    atomicAdd(&gsum[cc+0], a.x+b.x+c2.x+d2.x);
    atomicAdd(&gsum[cc+1], a.y+b.y+c2.y+d2.y);
    atomicAdd(&gsum[cc+2], a.z+b.z+c2.z+d2.z);
    atomicAdd(&gsum[cc+3], a.w+b.w+c2.w+d2.w);
    atomicAdd(&gsq [cc+0], e.x+f.x+g2.x+h2.x);
    atomicAdd(&gsq [cc+1], e.y+f.y+g2.y+h2.y);
    atomicAdd(&gsq [cc+2], e.z+f.z+g2.z+h2.z);
    atomicAdd(&gsq [cc+3], e.w+f.w+g2.w+h2.w);
  }
}

// -- norm apply + leaky + head-mean pool (bf16 in) with INLINE stats finalize --
// grid (NNODES/128, nn/256); params are d-length; column c -> channel c & (d-1).
__global__ __launch_bounds__(256) void k_norm_pool(const unsigned short* __restrict__ R,
                                                   unsigned short* __restrict__ Xn, // bf16 next-layer input (or null)
                                                   const float* __restrict__ gsum,
                                                   const float* __restrict__ gsq,
                                                   const float* __restrict__ gamma,
                                                   const float* __restrict__ beta,
                                                   const float* __restrict__ alpha,
                                                   float* __restrict__ pool, int d, int loff){
  int t = threadIdx.x, lane = t & 63, w = t >> 6;
  int c = blockIdx.y * 256 + lane * 4;
  int cm = c & (d - 1);                    // channel index (d-periodic), 4-aligned
  int nodeb = blockIdx.x * 128;
  int g = blockIdx.x >> 3;                 // 8 row-blocks per graph (1024 nodes/graph)
  int nn = 2 * d;
  const float Minv = 1.0f / (2.0f * (float)NNODES);
  float4 gg = *(const float4*)(gamma + cm);
  float4 bb = *(const float4*)(beta + cm);
  float4 aa = *(const float4*)(alpha + cm);
  float mmv[4], rrv[4];
  #pragma unroll
  for (int i = 0; i < 4; i++){
    float m = (gsum[cm+i] + gsum[cm+i+d]) * Minv;
    float q = (gsq [cm+i] + gsq [cm+i+d]) * Minv;
    float a = (i==0)?aa.x:(i==1)?aa.y:(i==2)?aa.z:aa.w;
    float var = q - a * m * m * (2.0f - a);
    mmv[i] = m; rrv[i] = rsqrtf(var + 1e-5f);
  }
  float am0 = aa.x*mmv[0], am1 = aa.y*mmv[1], am2 = aa.z*mmv[2], am3 = aa.w*mmv[3];
  const unsigned short* base = R + (size_t)(nodeb + w) * nn + c;
  unsigned short* xb = Xn ? (Xn + (size_t)(nodeb + w) * nn + c) : nullptr;
  float4 accp = make_float4(0,0,0,0);
  #pragma unroll 4
  for (int i = 0; i < 32; i++){
    bf16x4 bv = *(const bf16x4*)(base + (size_t)(i * 4) * nn);
    float vx = bf2f((unsigned short)bv[0]), vy = bf2f((unsigned short)bv[1]);
    float vz = bf2f((unsigned short)bv[2]), vw = bf2f((unsigned short)bv[3]);
    float y0 = gg.x*(vx-am0)*rrv[0] + bb.x; y0 = y0 >= 0.f ? y0 : 0.01f*y0;
    float y1 = gg.y*(vy-am1)*rrv[1] + bb.y; y1 = y1 >= 0.f ? y1 : 0.01f*y1;
    float y2 = gg.z*(vz-am2)*rrv[2] + bb.z; y2 = y2 >= 0.f ? y2 : 0.01f*y2;
    float y3 = gg.w*(vw-am3)*rrv[3] + bb.w; y3 = y3 >= 0.f ? y3 : 0.01f*y3;
    if (xb){
      ushort4 o; o.x = f2bf(y0); o.y = f2bf(y1); o.z = f2bf(y2); o.w = f2bf(y3);
      *(ushort4*)(xb + (size_t)(i * 4) * nn) = o;
    }
    accp.x += y0; accp.y += y1; accp.z += y2; accp.w += y3;
  }
  __shared__ float4 red[256];
  red[t] = accp; __syncthreads();
  if (t < 64){
    float4 a = red[t], b = red[t+64], c2 = red[t+128], d2 = red[t+192];
    int cc = blockIdx.y * 256 + t * 4;
    float* pb = pool + g * 896 + loff;
    atomicAdd(&pb[(cc+0) & (d-1)], 0.5f*(a.x+b.x+c2.x+d2.x));
    atomicAdd(&pb[(cc+1) & (d-1)], 0.5f*(a.y+b.y+c2.y+d2.y));
    atomicAdd(&pb[(cc+2) & (d-1)], 0.5f*(a.z+b.z+c2.z+d2.z));
    atomicAdd(&pb[(cc+3) & (d-1)], 0.5f*(a.w+b.w+c2.w+d2.w));
  }
}

__global__ void k_final(const float* __restrict__ pool, const float* __restrict__ counts,
                        float* __restrict__ out){
  int idx = blockIdx.x * 256 + threadIdx.x;
  if (idx >= NGRAPHS * 896) return;
  int g = idx / 896;
  float v = pool[idx] / counts[g];
  out[idx] = v >= 0.0f ? v : 0.01f * v;
}

// ---------------------------------------------------------------------------------------
extern "C" void kernel_launch(void* const* d_in, const int* in_sizes, int n_in,
                              void* d_out, int out_size, void* d_ws, size_t ws_size,
                              hipStream_t stream){
  const float* x0 = (const float*)d_in[0];
  const float *W[3], *AL[3], *AR[3], *RW[3], *GA[3], *BE[3], *ALP[3];
  for (int l = 0; l < 3; l++){
    const int b = 1 + l*7;
    W[l]  = (const float*)d_in[b+0];
    AL[l] = (const float*)d_in[b+1];
    AR[l] = (const float*)d_in[b+2];
    RW[l] = (const float*)d_in[b+3];
    GA[l] = (const float*)d_in[b+4];
    BE[l] = (const float*)d_in[b+5];
    ALP[l]= (const float*)d_in[b+6];
  }
  const int* esrc = (const int*)d_in[22];
  const int* edst = (const int*)d_in[23];
  const int* gid  = (const int*)d_in[24];
  float* out = (float*)d_out;

  char* p = (char*)d_ws;
  auto carve = [&](size_t bytes)->void*{
    void* r = (void*)p; p += (bytes + 255) & ~(size_t)255; return r;
  };
  unsigned short* HB = (unsigned short*)carve((size_t)NNODES * 1024 * 2);  // h bf16 [N, 2d]
  unsigned short* RB = (unsigned short*)carve((size_t)NNODES * 1024 * 2);  // r/out bf16 [N, 2d]
  unsigned short* X0b = (unsigned short*)carve((size_t)NNODES * 128 * 2);  // bf16 layer-0 input
  unsigned short* XA  = (unsigned short*)carve((size_t)NNODES * 256 * 2);  // bf16 y0
  unsigned short* XB  = (unsigned short*)carve((size_t)NNODES * 512 * 2);  // bf16 y1
  unsigned short* Wt  = (unsigned short*)carve((size_t)1024 * 512 * 2);    // bf16 W^T (max)
  unsigned short* RWt = (unsigned short*)carve((size_t)1024 * 512 * 2);    // bf16 resW^T (max)
  float* el     = (float*)carve((size_t)NNODES * 2 * 4);
  float* er     = (float*)carve((size_t)NNODES * 2 * 4);
  float* elp    = (float*)carve((size_t)NNODES * 16 * 4);    // el partials (G<=16)
  float* erp    = (float*)carve((size_t)NNODES * 16 * 4);    // er partials
  int*   deg    = (int*)  carve((size_t)NNODES * 4);
  int*   rowptr = (int*)  carve((size_t)(NNODES + 1) * 4);
  int*   cursor = (int*)  carve((size_t)NNODES * 4);
  int*   perm   = (int*)  carve((size_t)NEDGES * 4);
  float* stats  = (float*)carve(3 * 2048 * 4);               // per-layer gsum|gsq arenas
  float* pool   = (float*)carve((size_t)NGRAPHS * 896 * 4);
  float* countsF= (float*)carve((size_t)NGRAPHS * 4);
  (void)ws_size; (void)in_sizes; (void)n_in; (void)out_size;

  hipMemsetAsync(deg, 0, NNODES * 4, stream);
  hipMemsetAsync(pool, 0, NGRAPHS * 896 * 4, stream);
  hipMemsetAsync(countsF, 0, NGRAPHS * 4, stream);
  hipMemsetAsync(stats, 0, 3 * 2048 * 4, stream);

  k_deg    <<<NEDGES/256, 256, 0, stream>>>(edst, deg);
  k_scan   <<<1, 1024, 0, stream>>>(deg, rowptr, cursor);
  k_scatter<<<NEDGES/256, 256, 0, stream>>>(esrc, edst, cursor, perm);
  k_counts <<<NNODES/1024, 256, 0, stream>>>(gid, countsF);
  k_cvt    <<<(NNODES*128/4 + 255)/256, 256, 0, stream>>>(x0, X0b, NNODES*128/4);

  const unsigned short* xin = X0b;
  int loff = 0;
  const int dims[3] = {128, 256, 512};
  for (int l = 0; l < 3; l++){
    int d = dims[l], nn = 2*d;
    float* gsum = stats + l * 2048;
    float* gsq  = gsum + 1024;
    dim3 gt(nn/32, d/32, 2);
    k_cvt_t2<<<gt, 256, 0, stream>>>(W[l], RW[l], Wt, RWt, d, nn);
    dim3 gg(2*nn/128, NNODES/128);
    k_gemm2<<<gg, 256, 0, stream>>>(xin, Wt, RWt, HB, RB, AL[l], AR[l], elp, erp, d, nn);
    k_elred<<<NNODES/256, 256, 0, stream>>>(elp, erp, el, er, nn >> 6);
    if (d == 128){
      k_attn<128><<<NNODES/4, 256, 0, stream>>>(HB, RB, el, er, rowptr, perm);
    } else if (d == 256){
      k_attn<256><<<NNODES/4, 256, 0, stream>>>(HB, RB, el, er, rowptr, perm);
    } else {
      k_attn<512><<<NNODES/4, 256, 0, stream>>>(HB, RB, el, er, rowptr, perm);
    }
    dim3 gs(NNODES/128, nn/256);
    k_stats   <<<gs, 256, 0, stream>>>(RB, nn, gsum, gsq);
    unsigned short* xn = (l == 0) ? XA : (l == 1) ? XB : nullptr;
    k_norm_pool<<<gs, 256, 0, stream>>>(RB, xn, gsum, gsq, GA[l], BE[l], ALP[l], pool, d, loff);
    xin = xn; loff += d;
  }
  k_final<<<(NGRAPHS*896 + 255)/256, 256, 0, stream>>>(pool, countsF, out);
}

// Round 22
// 335.716 us; speedup vs baseline: 1.0862x; 1.0006x over previous
//
#include <hip/hip_runtime.h>
#include <math.h>

constexpr int NNODES  = 16384;
constexpr int NEDGES  = 131072;
constexpr int NGRAPHS = 16;

typedef short bf16x8 __attribute__((ext_vector_type(8)));
typedef short bf16x4 __attribute__((ext_vector_type(4)));
typedef float f32x4  __attribute__((ext_vector_type(4)));

__device__ __forceinline__ float leaky(float x, float s){ return x >= 0.0f ? x : s * x; }

__device__ __forceinline__ unsigned short f2bf(float f){
  unsigned u = __builtin_bit_cast(unsigned, f);
  u += 0x7FFFu + ((u >> 16) & 1u);          // round-to-nearest-even
  return (unsigned short)(u >> 16);
}
__device__ __forceinline__ float bf2f(unsigned short u){
  unsigned x = (unsigned)u << 16; return __builtin_bit_cast(float, x);
}

__device__ __forceinline__ void gload_lds16(const unsigned short* g, unsigned short* l){
  __builtin_amdgcn_global_load_lds((const __attribute__((address_space(1))) void*)g,
                                   (__attribute__((address_space(3))) void*)l, 16, 0, 0);
}

// ---------------- CSR build (edges fixed across layers; build once) ----------------
__global__ void k_deg(const int* __restrict__ dst, int* __restrict__ deg){
  int e = blockIdx.x * 256 + threadIdx.x;
  if (e < NEDGES) atomicAdd(&deg[dst[e]], 1);
}

__global__ __launch_bounds__(1024) void k_scan(const int* __restrict__ deg,
                                               int* __restrict__ rowptr,
                                               int* __restrict__ cursor){
  __shared__ int sums[1024];
  int t = threadIdx.x;
  int loc[16];
  int s = 0;
  #pragma unroll
  for (int i = 0; i < 16; i++){ loc[i] = deg[t*16 + i]; s += loc[i]; }
  sums[t] = s; __syncthreads();
  for (int off = 1; off < 1024; off <<= 1){
    int v = (t >= off) ? sums[t - off] : 0;
    __syncthreads();
    sums[t] += v;
    __syncthreads();
  }
  int base = (t > 0) ? sums[t-1] : 0;
  #pragma unroll
  for (int i = 0; i < 16; i++){
    rowptr[t*16 + i] = base; cursor[t*16 + i] = base; base += loc[i];
  }
  if (t == 1023) rowptr[NNODES] = base;
}

__global__ void k_scatter(const int* __restrict__ src, const int* __restrict__ dst,
                          int* __restrict__ cursor, int* __restrict__ perm){
  int e = blockIdx.x * 256 + threadIdx.x;
  if (e < NEDGES){ int p = atomicAdd(&cursor[dst[e]], 1); perm[p] = src[e]; }
}

// ---- graph-size counts: LDS histogram per block, one global atomic per (block,graph) ----
__global__ __launch_bounds__(256) void k_counts(const int* __restrict__ gid, float* __restrict__ counts){
  __shared__ int h[NGRAPHS];
  int t = threadIdx.x;
  if (t < NGRAPHS) h[t] = 0;
  __syncthreads();
  int base = blockIdx.x * 1024;
  #pragma unroll
  for (int i = 0; i < 4; i++)
    atomicAdd(&h[gid[base + t + i*256]], 1);
  __syncthreads();
  if (t < NGRAPHS && h[t] > 0) atomicAdd(&counts[t], (float)h[t]);
}

// ---------------- fp32 -> bf16 convert (contiguous) ----------------
__global__ void k_cvt(const float* __restrict__ in, unsigned short* __restrict__ out, int n4){
  int i = blockIdx.x * 256 + threadIdx.x;
  if (i >= n4) return;
  float4 v = ((const float4*)in)[i];
  ushort4 o; o.x = f2bf(v.x); o.y = f2bf(v.y); o.z = f2bf(v.z); o.w = f2bf(v.w);
  ((ushort4*)out)[i] = o;
}

// -------- fp32 [K][NN] -> bf16 transposed [NN][K], both W and RW in one launch --------
__global__ __launch_bounds__(256) void k_cvt_t2(const float* __restrict__ W,
                                                const float* __restrict__ RW,
                                                unsigned short* __restrict__ Wt,
                                                unsigned short* __restrict__ RWt,
                                                int K, int NN){
  __shared__ float tile[32][33];
  const float* src = blockIdx.z ? RW : W;
  unsigned short* dst = blockIdx.z ? RWt : Wt;
  int n0 = blockIdx.x * 32, k0 = blockIdx.y * 32;
  int tx = threadIdx.x & 31, ty = threadIdx.x >> 5;   // 32 x 8
  #pragma unroll
  for (int i = 0; i < 4; i++)
    tile[ty + i*8][tx] = src[(size_t)(k0 + ty + i*8) * NN + n0 + tx];
  __syncthreads();
  #pragma unroll
  for (int i = 0; i < 4; i++)
    dst[(size_t)(n0 + ty + i*8) * K + k0 + tx] = f2bf(tile[tx][ty + i*8]);
}

// ------- fused dual bf16 MFMA GEMM (BK=32, TRIPLE-buffered 2-deep prefetch) -------
// 128x128 tile, BK=32, 3 LDS buffers (48KB). Iter i: stage tile i+2 into
// buf[(i+2)%3]; s_waitcnt vmcnt(8) drains EXACTLY tile i (tiles i+1,i+2 = 8
// loads stay in flight) -> each tile gets TWO full iterations of latency
// cover (AITER/T4 depth>=2 pattern; depth-1 counted [R16] was neutral).
// Overwrite hazard safe: buf((i+2)%3) last read at iter i-1, whose closing
// barrier precedes iter i's staging. Swizzle 16B-slot ^= ((row>>1)&3)<<4.
// W-half epilogue: per-64-col el/er partial dots -> elp/erp (plain stores).
__global__ __launch_bounds__(256) void k_gemm2(const unsigned short* __restrict__ A,
                                               const unsigned short* __restrict__ Wt,
                                               const unsigned short* __restrict__ RWt,
                                               unsigned short* __restrict__ HB,
                                               unsigned short* __restrict__ RB,
                                               const float* __restrict__ al,
                                               const float* __restrict__ ar,
                                               float* __restrict__ elp,
                                               float* __restrict__ erp,
                                               int K, int NN){
  __shared__ unsigned short As[3][128 * 32];
  __shared__ unsigned short Bs[3][128 * 32];
  int t = threadIdx.x;
  int lane = t & 63, w = t >> 6;
  int nx  = gridDim.x;                       // 2*NN/128
  int nwg = nx * gridDim.y;                  // multiple of 8
  int bid = blockIdx.x + blockIdx.y * nx;
  int wg  = (bid & 7) * (nwg >> 3) + (bid >> 3);
  int bx = wg % nx, by = wg / nx;
  int half = nx >> 1;
  bool isW = bx < half;
  const unsigned short* Bt = isW ? Wt : RWt;
  int colB = (isW ? bx : bx - half) * 128;
  int rowA = by * 128;

  int wr = (w >> 1) * 64, wc = (w & 1) * 64;
  int l16 = lane & 15, lhi = lane >> 4;
  f32x4 acc[4][4] = {};

  // staging: 512 chunks of 16B per matrix/tile; thread t -> chunks t and t+256.
  int srow = t >> 2;                                    // 0..63; +64 for chunk t+256
  int skb  = ((t & 3) << 4) ^ (((srow >> 1) & 3) << 4); // bytes; same for srow+64
  const unsigned short* Ap = A  + (size_t)(rowA + srow) * K + (skb >> 1);
  const unsigned short* Bp = Bt + (size_t)(colB + srow) * K + (skb >> 1);
  size_t rstep = (size_t)64 * K;                        // +64 rows

  int nt = K >> 5;
  // prologue: stage tiles 0 and 1 (8 loads in flight; no drain)
  gload_lds16(Ap,              &As[0][t * 8]);
  gload_lds16(Ap + rstep,      &As[0][(t + 256) * 8]);
  gload_lds16(Bp,              &Bs[0][t * 8]);
  gload_lds16(Bp + rstep,      &Bs[0][(t + 256) * 8]);
  gload_lds16(Ap + 32,         &As[1][t * 8]);
  gload_lds16(Ap + 32 + rstep, &As[1][(t + 256) * 8]);
  gload_lds16(Bp + 32,         &Bs[1][t * 8]);
  gload_lds16(Bp + 32 + rstep, &Bs[1][(t + 256) * 8]);

  for (int tI = 0; tI < nt; tI++){
    int cur = tI % 3;
    if (tI + 2 < nt){
      int k0n = (tI + 2) << 5;
      int nb = (tI + 2) % 3;
      gload_lds16(Ap + k0n,         &As[nb][t * 8]);
      gload_lds16(Ap + k0n + rstep, &As[nb][(t + 256) * 8]);
      gload_lds16(Bp + k0n,         &Bs[nb][t * 8]);
      gload_lds16(Bp + k0n + rstep, &Bs[nb][(t + 256) * 8]);
      // outstanding = 12 (tiles tI, tI+1, tI+2); drain oldest 4 = tile tI
      asm volatile("s_waitcnt vmcnt(8)" ::: "memory");
    } else if (tI + 1 < nt){
      // outstanding = 8 (tiles tI, tI+1); drain tile tI
      asm volatile("s_waitcnt vmcnt(4)" ::: "memory");
    } else {
      asm volatile("s_waitcnt vmcnt(0)" ::: "memory");
    }
    __builtin_amdgcn_s_barrier();            // all waves drained tile tI's loads
    __builtin_amdgcn_sched_barrier(0);       // rule #18: pin reads below the wait
    int kb = lhi * 16;                       // this lane's 16B k-slot
    bf16x8 af[4], bfr[4];
    #pragma unroll
    for (int mi = 0; mi < 4; mi++){
      int row = wr + mi * 16 + l16;
      int off = row * 64 + (kb ^ (((row >> 1) & 3) << 4));
      af[mi] = *(const bf16x8*)((const char*)As[cur] + off);
    }
    #pragma unroll
    for (int ni = 0; ni < 4; ni++){
      int row = wc + ni * 16 + l16;
      int off = row * 64 + (kb ^ (((row >> 1) & 3) << 4));
      bfr[ni] = *(const bf16x8*)((const char*)Bs[cur] + off);
    }
    #pragma unroll
    for (int mi = 0; mi < 4; mi++)
      #pragma unroll
      for (int ni = 0; ni < 4; ni++)
        acc[mi][ni] = __builtin_amdgcn_mfma_f32_16x16x32_bf16(af[mi], bfr[ni], acc[mi][ni], 0, 0, 0);
    // closing barrier: all waves' reads of buf[cur] done before it is restaged
    // (buf[cur] is next written at iter tI+3 > tI, ordered after this barrier).
    __builtin_amdgcn_s_barrier();
  }

  unsigned short* C = isW ? HB : RB;
  #pragma unroll
  for (int mi = 0; mi < 4; mi++){
    #pragma unroll
    for (int j = 0; j < 4; j++){
      int r = rowA + wr + mi * 16 + lhi * 4 + j;
      unsigned short* Cp = C + (size_t)r * NN + colB + wc + l16;
      #pragma unroll
      for (int ni = 0; ni < 4; ni++)
        Cp[ni * 16] = f2bf(acc[mi][ni][j]);
    }
  }

  if (isW){
    int G = NN >> 6;                    // 64-col groups across nn
    int g64 = (colB + wc) >> 6;
    float alv[4], arv[4];
    #pragma unroll
    for (int ni = 0; ni < 4; ni++){
      int col = colB + wc + ni * 16 + l16;
      alv[ni] = al[col]; arv[ni] = ar[col];
    }
    #pragma unroll
    for (int mi = 0; mi < 4; mi++){
      #pragma unroll
      for (int j = 0; j < 4; j++){
        float pe = acc[mi][0][j]*alv[0] + acc[mi][1][j]*alv[1]
                 + acc[mi][2][j]*alv[2] + acc[mi][3][j]*alv[3];
        float pr = acc[mi][0][j]*arv[0] + acc[mi][1][j]*arv[1]
                 + acc[mi][2][j]*arv[2] + acc[mi][3][j]*arv[3];
        #pragma unroll
        for (int o = 8; o; o >>= 1){ pe += __shfl_xor(pe, o); pr += __shfl_xor(pr, o); }
        if (l16 == 0){
          int r = rowA + wr + mi * 16 + lhi * 4 + j;
          elp[(size_t)r * G + g64] = pe;
          erp[(size_t)r * G + g64] = pr;
        }
      }
    }
  }
}

// ---- reduce el/er partials: one thread per row; G = nn/64, half per head ----
__global__ void k_elred(const float* __restrict__ elp, const float* __restrict__ erp,
                        float* __restrict__ el, float* __restrict__ er, int G){
  int row = blockIdx.x * 256 + threadIdx.x;
  int half = G >> 1;
  float s0 = 0.f, s1 = 0.f, q0 = 0.f, q1 = 0.f;
  const float* ep = elp + (size_t)row * G;
  const float* rp = erp + (size_t)row * G;
  for (int i = 0; i < half; i++){ s0 += ep[i]; q0 += rp[i]; }
  for (int i = half; i < G; i++){ s1 += ep[i]; q1 += rp[i]; }
  el[row*2] = s0; el[row*2+1] = s1;
  er[row*2] = q0; er[row*2+1] = q1;
}

// ------- attention: one wave per destination node; 4-way edge-unrolled accumulate -------
template<int D>
__global__ __launch_bounds__(256) void k_attn(const unsigned short* __restrict__ HB,
                                              unsigned short* __restrict__ RB,
                                              const float* __restrict__ el,
                                              const float* __restrict__ er,
                                              const int* __restrict__ rowptr,
                                              const int* __restrict__ perm){
  constexpr int ITER = (2*D)/256;
  int wid = threadIdx.x >> 6, lane = threadIdx.x & 63;
  int nb = (blockIdx.x & 7) * (NNODES/4/8) + (blockIdx.x >> 3);   // bijective: 4096 = 8*512
  int n = nb * 4 + wid;
  int r0 = rowptr[n], r1 = rowptr[n+1];
  if (r0 == r1) return;   // no in-edges: output = residual already in RB
  float er0 = er[n*2], er1 = er[n*2+1];
  float mx0 = -1e30f, mx1 = -1e30f;
  for (int e = r0 + lane; e < r1; e += 64){
    int s = perm[e];
    mx0 = fmaxf(mx0, leaky(el[s*2]   + er0, 0.2f));
    mx1 = fmaxf(mx1, leaky(el[s*2+1] + er1, 0.2f));
  }
  #pragma unroll
  for (int o = 32; o; o >>= 1){ mx0 = fmaxf(mx0, __shfl_xor(mx0, o)); mx1 = fmaxf(mx1, __shfl_xor(mx1, o)); }
  float sm0 = 0.0f, sm1 = 0.0f;
  for (int e = r0 + lane; e < r1; e += 64){
    int s = perm[e];
    sm0 += expf(leaky(el[s*2]   + er0, 0.2f) - mx0);
    sm1 += expf(leaky(el[s*2+1] + er1, 0.2f) - mx1);
  }
  #pragma unroll
  for (int o = 32; o; o >>= 1){ sm0 += __shfl_xor(sm0, o); sm1 += __shfl_xor(sm1, o); }
  float inv0 = 1.0f / sm0, inv1 = 1.0f / sm1;
  float acc[ITER][4];
  #pragma unroll
  for (int j = 0; j < ITER; j++)
    #pragma unroll
    for (int i = 0; i < 4; i++) acc[j][i] = 0.0f;
  int e = r0;
  // 4-way unroll: 4 edges' gathers issued together -> latency overlapped
  for (; e + 3 < r1; e += 4){
    int s0 = perm[e], s1 = perm[e+1], s2 = perm[e+2], s3 = perm[e+3];
    float w00 = expf(leaky(el[s0*2]   + er0, 0.2f) - mx0) * inv0;
    float w01 = expf(leaky(el[s0*2+1] + er1, 0.2f) - mx1) * inv1;
    float w10 = expf(leaky(el[s1*2]   + er0, 0.2f) - mx0) * inv0;
    float w11 = expf(leaky(el[s1*2+1] + er1, 0.2f) - mx1) * inv1;
    float w20 = expf(leaky(el[s2*2]   + er0, 0.2f) - mx0) * inv0;
    float w21 = expf(leaky(el[s2*2+1] + er1, 0.2f) - mx1) * inv1;
    float w30 = expf(leaky(el[s3*2]   + er0, 0.2f) - mx0) * inv0;
    float w31 = expf(leaky(el[s3*2+1] + er1, 0.2f) - mx1) * inv1;
    const unsigned short* h0 = HB + (size_t)s0 * (2*D);
    const unsigned short* h1 = HB + (size_t)s1 * (2*D);
    const unsigned short* h2 = HB + (size_t)s2 * (2*D);
    const unsigned short* h3 = HB + (size_t)s3 * (2*D);
    #pragma unroll
    for (int j = 0; j < ITER; j++){
      int base = j*256 + lane*4;
      bf16x4 v0 = *(const bf16x4*)(h0 + base);
      bf16x4 v1 = *(const bf16x4*)(h1 + base);
      bf16x4 v2 = *(const bf16x4*)(h2 + base);
      bf16x4 v3 = *(const bf16x4*)(h3 + base);
      float a0 = (base < D) ? w00 : w01;
      float a1 = (base < D) ? w10 : w11;
      float a2 = (base < D) ? w20 : w21;
      float a3 = (base < D) ? w30 : w31;
      #pragma unroll
      for (int i = 0; i < 4; i++)
        acc[j][i] += a0 * bf2f((unsigned short)v0[i]) + a1 * bf2f((unsigned short)v1[i])
                   + a2 * bf2f((unsigned short)v2[i]) + a3 * bf2f((unsigned short)v3[i]);
    }
  }
  for (; e < r1; ++e){
    int s = perm[e];
    float a0 = expf(leaky(el[s*2]   + er0, 0.2f) - mx0) * inv0;
    float a1 = expf(leaky(el[s*2+1] + er1, 0.2f) - mx1) * inv1;
    const unsigned short* hrow = HB + (size_t)s * (2*D);
    #pragma unroll
    for (int j = 0; j < ITER; j++){
      int base = j*256 + lane*4;
      bf16x4 v = *(const bf16x4*)(hrow + base);
      float a = (base < D) ? a0 : a1;
      #pragma unroll
      for (int i = 0; i < 4; i++)
        acc[j][i] += a * bf2f((unsigned short)v[i]);
    }
  }
  unsigned short* rrow = RB + (size_t)n * (2*D);
  #pragma unroll
  for (int j = 0; j < ITER; j++){
    int base = j*256 + lane*4;
    bf16x4 r = *(bf16x4*)(rrow + base);
    ushort4 o;
    o.x = f2bf(bf2f((unsigned short)r[0]) + acc[j][0]);
    o.y = f2bf(bf2f((unsigned short)r[1]) + acc[j][1]);
    o.z = f2bf(bf2f((unsigned short)r[2]) + acc[j][2]);
    o.w = f2bf(bf2f((unsigned short)r[3]) + acc[j][3]);
    *(ushort4*)(rrow + base) = o;
  }
}

// ------- GraphNorm stats (bf16 in): grid (NNODES/128, nn/256); lane owns 4 cols -------
__global__ __launch_bounds__(256) void k_stats(const unsigned short* __restrict__ R, int nn,
                                               float* __restrict__ gsum, float* __restrict__ gsq){
  int t = threadIdx.x, lane = t & 63, w = t >> 6;
  int c = blockIdx.y * 256 + lane * 4;
  const unsigned short* base = R + (size_t)(blockIdx.x * 128 + w) * nn + c;
  float4 s = make_float4(0,0,0,0), q = make_float4(0,0,0,0);
  #pragma unroll 4
  for (int i = 0; i < 32; i++){
    bf16x4 bv = *(const bf16x4*)(base + (size_t)(i * 4) * nn);
    float vx = bf2f((unsigned short)bv[0]), vy = bf2f((unsigned short)bv[1]);
    float vz = bf2f((unsigned short)bv[2]), vw = bf2f((unsigned short)bv[3]);
    s.x += vx; s.y += vy; s.z += vz; s.w += vw;
    q.x += vx*vx; q.y += vy*vy; q.z += vz*vz; q.w += vw*vw;
  }
  __shared__ float4 rs[256], rq[256];
  rs[t] = s; rq[t] = q; __syncthreads();
  if (t < 64){
    float4 a = rs[t], b = rs[t+64], c2 = rs[t+128], d2 = rs[t+192];
    float4 e = rq[t], f = rq[t+64], g2 = rq[t+128], h2 = rq[t+192];
    int cc = blockIdx.y * 256 + t * 4;
    atomicAdd(&gsum[cc+0], a.x+b.x+c2.x+d2.x);
    atomicAdd(&gsum[cc+1], a.y+b.y+c2.y+d2.y);
    atomicAdd(&gsum[cc+2], a.z+b.z+c2.z+d2.z);
    atomicAdd(&gsum[cc+3], a.w+b.w+c2.w+d2.w);
    atomicAdd(&gsq [cc+0], e.x+f.x+g2.x+h2.x);
    atomicAdd(&gsq [cc+1], e.y+f.y+g2.y+h2.y);
    atomicAdd(&gsq [cc+2], e.z+f.z+g2.z+h2.z);
    atomicAdd(&gsq [cc+3], e.w+f.w+g2.w+h2.w);
  }
}

// -- norm apply + leaky + head-mean pool (bf16 in) with INLINE stats finalize --
// grid (NNODES/128, nn/256); params are d-length; column c -> channel c & (d-1).
__global__ __launch_bounds__(256) void k_norm_pool(const unsigned short* __restrict__ R,
                                                   unsigned short* __restrict__ Xn, // bf16 next-layer input (or null)
                                                   const float* __restrict__ gsum,
                                                   const float* __restrict__ gsq,
                                                   const float* __restrict__ gamma,
                                                   const float* __restrict__ beta,
                                                   const float* __restrict__ alpha,
                                                   float* __restrict__ pool, int d, int loff){
  int t = threadIdx.x, lane = t & 63, w = t >> 6;
  int c = blockIdx.y * 256 + lane * 4;
  int cm = c & (d - 1);                    // channel index (d-periodic), 4-aligned
  int nodeb = blockIdx.x * 128;
  int g = blockIdx.x >> 3;                 // 8 row-blocks per graph (1024 nodes/graph)
  int nn = 2 * d;
  const float Minv = 1.0f / (2.0f * (float)NNODES);
  float4 gg = *(const float4*)(gamma + cm);
  float4 bb = *(const float4*)(beta + cm);
  float4 aa = *(const float4*)(alpha + cm);
  float mmv[4], rrv[4];
  #pragma unroll
  for (int i = 0; i < 4; i++){
    float m = (gsum[cm+i] + gsum[cm+i+d]) * Minv;
    float q = (gsq [cm+i] + gsq [cm+i+d]) * Minv;
    float a = (i==0)?aa.x:(i==1)?aa.y:(i==2)?aa.z:aa.w;
    float var = q - a * m * m * (2.0f - a);
    mmv[i] = m; rrv[i] = rsqrtf(var + 1e-5f);
  }
  float am0 = aa.x*mmv[0], am1 = aa.y*mmv[1], am2 = aa.z*mmv[2], am3 = aa.w*mmv[3];
  const unsigned short* base = R + (size_t)(nodeb + w) * nn + c;
  unsigned short* xb = Xn ? (Xn + (size_t)(nodeb + w) * nn + c) : nullptr;
  float4 accp = make_float4(0,0,0,0);
  #pragma unroll 4
  for (int i = 0; i < 32; i++){
    bf16x4 bv = *(const bf16x4*)(base + (size_t)(i * 4) * nn);
    float vx = bf2f((unsigned short)bv[0]), vy = bf2f((unsigned short)bv[1]);
    float vz = bf2f((unsigned short)bv[2]), vw = bf2f((unsigned short)bv[3]);
    float y0 = gg.x*(vx-am0)*rrv[0] + bb.x; y0 = y0 >= 0.f ? y0 : 0.01f*y0;
    float y1 = gg.y*(vy-am1)*rrv[1] + bb.y; y1 = y1 >= 0.f ? y1 : 0.01f*y1;
    float y2 = gg.z*(vz-am2)*rrv[2] + bb.z; y2 = y2 >= 0.f ? y2 : 0.01f*y2;
    float y3 = gg.w*(vw-am3)*rrv[3] + bb.w; y3 = y3 >= 0.f ? y3 : 0.01f*y3;
    if (xb){
      ushort4 o; o.x = f2bf(y0); o.y = f2bf(y1); o.z = f2bf(y2); o.w = f2bf(y3);
      *(ushort4*)(xb + (size_t)(i * 4) * nn) = o;
    }
    accp.x += y0; accp.y += y1; accp.z += y2; accp.w += y3;
  }
  __shared__ float4 red[256];
  red[t] = accp; __syncthreads();
  if (t < 64){
    float4 a = red[t], b = red[t+64], c2 = red[t+128], d2 = red[t+192];
    int cc = blockIdx.y * 256 + t * 4;
    float* pb = pool + g * 896 + loff;
    atomicAdd(&pb[(cc+0) & (d-1)], 0.5f*(a.x+b.x+c2.x+d2.x));
    atomicAdd(&pb[(cc+1) & (d-1)], 0.5f*(a.y+b.y+c2.y+d2.y));
    atomicAdd(&pb[(cc+2) & (d-1)], 0.5f*(a.z+b.z+c2.z+d2.z));
    atomicAdd(&pb[(cc+3) & (d-1)], 0.5f*(a.w+b.w+c2.w+d2.w));
  }
}

__global__ void k_final(const float* __restrict__ pool, const float* __restrict__ counts,
                        float* __restrict__ out){
  int idx = blockIdx.x * 256 + threadIdx.x;
  if (idx >= NGRAPHS * 896) return;
  int g = idx / 896;
  float v = pool[idx] / counts[g];
  out[idx] = v >= 0.0f ? v : 0.01f * v;
}

// ---------------------------------------------------------------------------------------
extern "C" void kernel_launch(void* const* d_in, const int* in_sizes, int n_in,
                              void* d_out, int out_size, void* d_ws, size_t ws_size,
                              hipStream_t stream){
  const float* x0 = (const float*)d_in[0];
  const float *W[3], *AL[3], *AR[3], *RW[3], *GA[3], *BE[3], *ALP[3];
  for (int l = 0; l < 3; l++){
    const int b = 1 + l*7;
    W[l]  = (const float*)d_in[b+0];
    AL[l] = (const float*)d_in[b+1];
    AR[l] = (const float*)d_in[b+2];
    RW[l] = (const float*)d_in[b+3];
    GA[l] = (const float*)d_in[b+4];
    BE[l] = (const float*)d_in[b+5];
    ALP[l]= (const float*)d_in[b+6];
  }
  const int* esrc = (const int*)d_in[22];
  const int* edst = (const int*)d_in[23];
  const int* gid  = (const int*)d_in[24];
  float* out = (float*)d_out;

  char* p = (char*)d_ws;
  auto carve = [&](size_t bytes)->void*{
    void* r = (void*)p; p += (bytes + 255) & ~(size_t)255; return r;
  };
  unsigned short* HB = (unsigned short*)carve((size_t)NNODES * 1024 * 2);  // h bf16 [N, 2d]
  unsigned short* RB = (unsigned short*)carve((size_t)NNODES * 1024 * 2);  // r/out bf16 [N, 2d]
  unsigned short* X0b = (unsigned short*)carve((size_t)NNODES * 128 * 2);  // bf16 layer-0 input
  unsigned short* XA  = (unsigned short*)carve((size_t)NNODES * 256 * 2);  // bf16 y0
  unsigned short* XB  = (unsigned short*)carve((size_t)NNODES * 512 * 2);  // bf16 y1
  unsigned short* Wt  = (unsigned short*)carve((size_t)1024 * 512 * 2);    // bf16 W^T (max)
  unsigned short* RWt = (unsigned short*)carve((size_t)1024 * 512 * 2);    // bf16 resW^T (max)
  float* el     = (float*)carve((size_t)NNODES * 2 * 4);
  float* er     = (float*)carve((size_t)NNODES * 2 * 4);
  float* elp    = (float*)carve((size_t)NNODES * 16 * 4);    // el partials (G<=16)
  float* erp    = (float*)carve((size_t)NNODES * 16 * 4);    // er partials
  int*   deg    = (int*)  carve((size_t)NNODES * 4);
  int*   rowptr = (int*)  carve((size_t)(NNODES + 1) * 4);
  int*   cursor = (int*)  carve((size_t)NNODES * 4);
  int*   perm   = (int*)  carve((size_t)NEDGES * 4);
  float* stats  = (float*)carve(3 * 2048 * 4);               // per-layer gsum|gsq arenas
  float* pool   = (float*)carve((size_t)NGRAPHS * 896 * 4);
  float* countsF= (float*)carve((size_t)NGRAPHS * 4);
  (void)ws_size; (void)in_sizes; (void)n_in; (void)out_size;

  hipMemsetAsync(deg, 0, NNODES * 4, stream);
  hipMemsetAsync(pool, 0, NGRAPHS * 896 * 4, stream);
  hipMemsetAsync(countsF, 0, NGRAPHS * 4, stream);
  hipMemsetAsync(stats, 0, 3 * 2048 * 4, stream);

  k_deg    <<<NEDGES/256, 256, 0, stream>>>(edst, deg);
  k_scan   <<<1, 1024, 0, stream>>>(deg, rowptr, cursor);
  k_scatter<<<NEDGES/256, 256, 0, stream>>>(esrc, edst, cursor, perm);
  k_counts <<<NNODES/1024, 256, 0, stream>>>(gid, countsF);
  k_cvt    <<<(NNODES*128/4 + 255)/256, 256, 0, stream>>>(x0, X0b, NNODES*128/4);

  const unsigned short* xin = X0b;
  int loff = 0;
  const int dims[3] = {128, 256, 512};
  for (int l = 0; l < 3; l++){
    int d = dims[l], nn = 2*d;
    float* gsum = stats + l * 2048;
    float* gsq  = gsum + 1024;
    dim3 gt(nn/32, d/32, 2);
    k_cvt_t2<<<gt, 256, 0, stream>>>(W[l], RW[l], Wt, RWt, d, nn);
    dim3 gg(2*nn/128, NNODES/128);
    k_gemm2<<<gg, 256, 0, stream>>>(xin, Wt, RWt, HB, RB, AL[l], AR[l], elp, erp, d, nn);
    k_elred<<<NNODES/256, 256, 0, stream>>>(elp, erp, el, er, nn >> 6);
    if (d == 128){
      k_attn<128><<<NNODES/4, 256, 0, stream>>>(HB, RB, el, er, rowptr, perm);
    } else if (d == 256){
      k_attn<256><<<NNODES/4, 256, 0, stream>>>(HB, RB, el, er, rowptr, perm);
    } else {
      k_attn<512><<<NNODES/4, 256, 0, stream>>>(HB, RB, el, er, rowptr, perm);
    }
    dim3 gs(NNODES/128, nn/256);
    k_stats   <<<gs, 256, 0, stream>>>(RB, nn, gsum, gsq);
    unsigned short* xn = (l == 0) ? XA : (l == 1) ? XB : nullptr;
    k_norm_pool<<<gs, 256, 0, stream>>>(RB, xn, gsum, gsq, GA[l], BE[l], ALP[l], pool, d, loff);
    xin = xn; loff += d;
  }
  k_final<<<(NGRAPHS*896 + 255)/256, 256, 0, stream>>>(pool, countsF, out);
}

// Round 23
// 333.851 us; speedup vs baseline: 1.0922x; 1.0056x over previous
//
#include <hip/hip_runtime.h>
#include <math.h>

constexpr int NNODES  = 16384;
constexpr int NEDGES  = 131072;
constexpr int NGRAPHS = 16;

typedef short bf16x8 __attribute__((ext_vector_type(8)));
typedef short bf16x4 __attribute__((ext_vector_type(4)));
typedef float f32x4  __attribute__((ext_vector_type(4)));

__device__ __forceinline__ float leaky(float x, float s){ return x >= 0.0f ? x : s * x; }

__device__ __forceinline__ unsigned short f2bf(float f){
  unsigned u = __builtin_bit_cast(unsigned, f);
  u += 0x7FFFu + ((u >> 16) & 1u);          // round-to-nearest-even
  return (unsigned short)(u >> 16);
}
__device__ __forceinline__ float bf2f(unsigned short u){
  unsigned x = (unsigned)u << 16; return __builtin_bit_cast(float, x);
}

__device__ __forceinline__ void gload_lds16(const unsigned short* g, unsigned short* l){
  __builtin_amdgcn_global_load_lds((const __attribute__((address_space(1))) void*)g,
                                   (__attribute__((address_space(3))) void*)l, 16, 0, 0);
}

// ---------------- CSR build (edges fixed across layers; build once) ----------------
__global__ void k_deg(const int* __restrict__ dst, int* __restrict__ deg){
  int e = blockIdx.x * 256 + threadIdx.x;
  if (e < NEDGES) atomicAdd(&deg[dst[e]], 1);
}

__global__ __launch_bounds__(1024) void k_scan(const int* __restrict__ deg,
                                               int* __restrict__ rowptr,
                                               int* __restrict__ cursor){
  __shared__ int sums[1024];
  int t = threadIdx.x;
  int loc[16];
  int s = 0;
  #pragma unroll
  for (int i = 0; i < 16; i++){ loc[i] = deg[t*16 + i]; s += loc[i]; }
  sums[t] = s; __syncthreads();
  for (int off = 1; off < 1024; off <<= 1){
    int v = (t >= off) ? sums[t - off] : 0;
    __syncthreads();
    sums[t] += v;
    __syncthreads();
  }
  int base = (t > 0) ? sums[t-1] : 0;
  #pragma unroll
  for (int i = 0; i < 16; i++){
    rowptr[t*16 + i] = base; cursor[t*16 + i] = base; base += loc[i];
  }
  if (t == 1023) rowptr[NNODES] = base;
}

__global__ void k_scatter(const int* __restrict__ src, const int* __restrict__ dst,
                          int* __restrict__ cursor, int* __restrict__ perm){
  int e = blockIdx.x * 256 + threadIdx.x;
  if (e < NEDGES){ int p = atomicAdd(&cursor[dst[e]], 1); perm[p] = src[e]; }
}

// ---- graph-size counts: LDS histogram per block, one global atomic per (block,graph) ----
__global__ __launch_bounds__(256) void k_counts(const int* __restrict__ gid, float* __restrict__ counts){
  __shared__ int h[NGRAPHS];
  int t = threadIdx.x;
  if (t < NGRAPHS) h[t] = 0;
  __syncthreads();
  int base = blockIdx.x * 1024;
  #pragma unroll
  for (int i = 0; i < 4; i++)
    atomicAdd(&h[gid[base + t + i*256]], 1);
  __syncthreads();
  if (t < NGRAPHS && h[t] > 0) atomicAdd(&counts[t], (float)h[t]);
}

// ---------------- fp32 -> bf16 convert (contiguous) ----------------
__global__ void k_cvt(const float* __restrict__ in, unsigned short* __restrict__ out, int n4){
  int i = blockIdx.x * 256 + threadIdx.x;
  if (i >= n4) return;
  float4 v = ((const float4*)in)[i];
  ushort4 o; o.x = f2bf(v.x); o.y = f2bf(v.y); o.z = f2bf(v.z); o.w = f2bf(v.w);
  ((ushort4*)out)[i] = o;
}

// -------- fp32 [K][NN] -> bf16 transposed [NN][K], both W and RW in one launch --------
__global__ __launch_bounds__(256) void k_cvt_t2(const float* __restrict__ W,
                                                const float* __restrict__ RW,
                                                unsigned short* __restrict__ Wt,
                                                unsigned short* __restrict__ RWt,
                                                int K, int NN){
  __shared__ float tile[32][33];
  const float* src = blockIdx.z ? RW : W;
  unsigned short* dst = blockIdx.z ? RWt : Wt;
  int n0 = blockIdx.x * 32, k0 = blockIdx.y * 32;
  int tx = threadIdx.x & 31, ty = threadIdx.x >> 5;   // 32 x 8
  #pragma unroll
  for (int i = 0; i < 4; i++)
    tile[ty + i*8][tx] = src[(size_t)(k0 + ty + i*8) * NN + n0 + tx];
  __syncthreads();
  #pragma unroll
  for (int i = 0; i < 4; i++)
    dst[(size_t)(n0 + ty + i*8) * K + k0 + tx] = f2bf(tile[tx][ty + i*8]);
}

// ------- fused dual bf16 MFMA GEMM (BK=32, TRIPLE-buffered 2-deep prefetch) -------
// 128x128 tile, BK=32, 3 LDS buffers (48KB). launch_bounds(256,3): regs/thread
// = 72 VGPR + 64 AGPR = 136 <= 512/3=170 cap -> NO spill (unlike R20's (256,5)),
// but allocator/dispatcher now targets 3 blocks/CU residency (8 blocks/CU in
// 8/3 rounds instead of 8/2 -> predicted ~25% faster if the 3rd block lands).
// Iter i: stage tile i+2; vmcnt(8) drains exactly tile i. Swizzle
// 16B-slot ^= ((row>>1)&3)<<4. W-half epilogue: el/er partials (plain stores).
__global__ __launch_bounds__(256, 3) void k_gemm2(const unsigned short* __restrict__ A,
                                               const unsigned short* __restrict__ Wt,
                                               const unsigned short* __restrict__ RWt,
                                               unsigned short* __restrict__ HB,
                                               unsigned short* __restrict__ RB,
                                               const float* __restrict__ al,
                                               const float* __restrict__ ar,
                                               float* __restrict__ elp,
                                               float* __restrict__ erp,
                                               int K, int NN){
  __shared__ unsigned short As[3][128 * 32];
  __shared__ unsigned short Bs[3][128 * 32];
  int t = threadIdx.x;
  int lane = t & 63, w = t >> 6;
  int nx  = gridDim.x;                       // 2*NN/128
  int nwg = nx * gridDim.y;                  // multiple of 8
  int bid = blockIdx.x + blockIdx.y * nx;
  int wg  = (bid & 7) * (nwg >> 3) + (bid >> 3);
  int bx = wg % nx, by = wg / nx;
  int half = nx >> 1;
  bool isW = bx < half;
  const unsigned short* Bt = isW ? Wt : RWt;
  int colB = (isW ? bx : bx - half) * 128;
  int rowA = by * 128;

  int wr = (w >> 1) * 64, wc = (w & 1) * 64;
  int l16 = lane & 15, lhi = lane >> 4;
  f32x4 acc[4][4] = {};

  // staging: 512 chunks of 16B per matrix/tile; thread t -> chunks t and t+256.
  int srow = t >> 2;                                    // 0..63; +64 for chunk t+256
  int skb  = ((t & 3) << 4) ^ (((srow >> 1) & 3) << 4); // bytes; same for srow+64
  const unsigned short* Ap = A  + (size_t)(rowA + srow) * K + (skb >> 1);
  const unsigned short* Bp = Bt + (size_t)(colB + srow) * K + (skb >> 1);
  size_t rstep = (size_t)64 * K;                        // +64 rows

  int nt = K >> 5;
  // prologue: stage tiles 0 and 1 (8 loads in flight; no drain)
  gload_lds16(Ap,              &As[0][t * 8]);
  gload_lds16(Ap + rstep,      &As[0][(t + 256) * 8]);
  gload_lds16(Bp,              &Bs[0][t * 8]);
  gload_lds16(Bp + rstep,      &Bs[0][(t + 256) * 8]);
  gload_lds16(Ap + 32,         &As[1][t * 8]);
  gload_lds16(Ap + 32 + rstep, &As[1][(t + 256) * 8]);
  gload_lds16(Bp + 32,         &Bs[1][t * 8]);
  gload_lds16(Bp + 32 + rstep, &Bs[1][(t + 256) * 8]);

  for (int tI = 0; tI < nt; tI++){
    int cur = tI % 3;
    if (tI + 2 < nt){
      int k0n = (tI + 2) << 5;
      int nb = (tI + 2) % 3;
      gload_lds16(Ap + k0n,         &As[nb][t * 8]);
      gload_lds16(Ap + k0n + rstep, &As[nb][(t + 256) * 8]);
      gload_lds16(Bp + k0n,         &Bs[nb][t * 8]);
      gload_lds16(Bp + k0n + rstep, &Bs[nb][(t + 256) * 8]);
      // outstanding = 12 (tiles tI, tI+1, tI+2); drain oldest 4 = tile tI
      asm volatile("s_waitcnt vmcnt(8)" ::: "memory");
    } else if (tI + 1 < nt){
      asm volatile("s_waitcnt vmcnt(4)" ::: "memory");
    } else {
      asm volatile("s_waitcnt vmcnt(0)" ::: "memory");
    }
    __builtin_amdgcn_s_barrier();            // all waves drained tile tI's loads
    __builtin_amdgcn_sched_barrier(0);       // rule #18: pin reads below the wait
    int kb = lhi * 16;                       // this lane's 16B k-slot
    bf16x8 af[4], bfr[4];
    #pragma unroll
    for (int mi = 0; mi < 4; mi++){
      int row = wr + mi * 16 + l16;
      int off = row * 64 + (kb ^ (((row >> 1) & 3) << 4));
      af[mi] = *(const bf16x8*)((const char*)As[cur] + off);
    }
    #pragma unroll
    for (int ni = 0; ni < 4; ni++){
      int row = wc + ni * 16 + l16;
      int off = row * 64 + (kb ^ (((row >> 1) & 3) << 4));
      bfr[ni] = *(const bf16x8*)((const char*)Bs[cur] + off);
    }
    #pragma unroll
    for (int mi = 0; mi < 4; mi++)
      #pragma unroll
      for (int ni = 0; ni < 4; ni++)
        acc[mi][ni] = __builtin_amdgcn_mfma_f32_16x16x32_bf16(af[mi], bfr[ni], acc[mi][ni], 0, 0, 0);
    // closing barrier: reads of buf[cur] done before it is restaged (iter tI+3)
    __builtin_amdgcn_s_barrier();
  }

  unsigned short* C = isW ? HB : RB;
  #pragma unroll
  for (int mi = 0; mi < 4; mi++){
    #pragma unroll
    for (int j = 0; j < 4; j++){
      int r = rowA + wr + mi * 16 + lhi * 4 + j;
      unsigned short* Cp = C + (size_t)r * NN + colB + wc + l16;
      #pragma unroll
      for (int ni = 0; ni < 4; ni++)
        Cp[ni * 16] = f2bf(acc[mi][ni][j]);
    }
  }

  if (isW){
    int G = NN >> 6;                    // 64-col groups across nn
    int g64 = (colB + wc) >> 6;
    float alv[4], arv[4];
    #pragma unroll
    for (int ni = 0; ni < 4; ni++){
      int col = colB + wc + ni * 16 + l16;
      alv[ni] = al[col]; arv[ni] = ar[col];
    }
    #pragma unroll
    for (int mi = 0; mi < 4; mi++){
      #pragma unroll
      for (int j = 0; j < 4; j++){
        float pe = acc[mi][0][j]*alv[0] + acc[mi][1][j]*alv[1]
                 + acc[mi][2][j]*alv[2] + acc[mi][3][j]*alv[3];
        float pr = acc[mi][0][j]*arv[0] + acc[mi][1][j]*arv[1]
                 + acc[mi][2][j]*arv[2] + acc[mi][3][j]*arv[3];
        #pragma unroll
        for (int o = 8; o; o >>= 1){ pe += __shfl_xor(pe, o); pr += __shfl_xor(pr, o); }
        if (l16 == 0){
          int r = rowA + wr + mi * 16 + lhi * 4 + j;
          elp[(size_t)r * G + g64] = pe;
          erp[(size_t)r * G + g64] = pr;
        }
      }
    }
  }
}

// ---- reduce el/er partials: one thread per row; G = nn/64, half per head ----
__global__ void k_elred(const float* __restrict__ elp, const float* __restrict__ erp,
                        float* __restrict__ el, float* __restrict__ er, int G){
  int row = blockIdx.x * 256 + threadIdx.x;
  int half = G >> 1;
  float s0 = 0.f, s1 = 0.f, q0 = 0.f, q1 = 0.f;
  const float* ep = elp + (size_t)row * G;
  const float* rp = erp + (size_t)row * G;
  for (int i = 0; i < half; i++){ s0 += ep[i]; q0 += rp[i]; }
  for (int i = half; i < G; i++){ s1 += ep[i]; q1 += rp[i]; }
  el[row*2] = s0; el[row*2+1] = s1;
  er[row*2] = q0; er[row*2+1] = q1;
}

// ------- attention: one wave per destination node; 4-way edge-unrolled accumulate -------
template<int D>
__global__ __launch_bounds__(256) void k_attn(const unsigned short* __restrict__ HB,
                                              unsigned short* __restrict__ RB,
                                              const float* __restrict__ el,
                                              const float* __restrict__ er,
                                              const int* __restrict__ rowptr,
                                              const int* __restrict__ perm){
  constexpr int ITER = (2*D)/256;
  int wid = threadIdx.x >> 6, lane = threadIdx.x & 63;
  int nb = (blockIdx.x & 7) * (NNODES/4/8) + (blockIdx.x >> 3);   // bijective: 4096 = 8*512
  int n = nb * 4 + wid;
  int r0 = rowptr[n], r1 = rowptr[n+1];
  if (r0 == r1) return;   // no in-edges: output = residual already in RB
  float er0 = er[n*2], er1 = er[n*2+1];
  float mx0 = -1e30f, mx1 = -1e30f;
  for (int e = r0 + lane; e < r1; e += 64){
    int s = perm[e];
    mx0 = fmaxf(mx0, leaky(el[s*2]   + er0, 0.2f));
    mx1 = fmaxf(mx1, leaky(el[s*2+1] + er1, 0.2f));
  }
  #pragma unroll
  for (int o = 32; o; o >>= 1){ mx0 = fmaxf(mx0, __shfl_xor(mx0, o)); mx1 = fmaxf(mx1, __shfl_xor(mx1, o)); }
  float sm0 = 0.0f, sm1 = 0.0f;
  for (int e = r0 + lane; e < r1; e += 64){
    int s = perm[e];
    sm0 += expf(leaky(el[s*2]   + er0, 0.2f) - mx0);
    sm1 += expf(leaky(el[s*2+1] + er1, 0.2f) - mx1);
  }
  #pragma unroll
  for (int o = 32; o; o >>= 1){ sm0 += __shfl_xor(sm0, o); sm1 += __shfl_xor(sm1, o); }
  float inv0 = 1.0f / sm0, inv1 = 1.0f / sm1;
  float acc[ITER][4];
  #pragma unroll
  for (int j = 0; j < ITER; j++)
    #pragma unroll
    for (int i = 0; i < 4; i++) acc[j][i] = 0.0f;
  int e = r0;
  // 4-way unroll: 4 edges' gathers issued together -> latency overlapped
  for (; e + 3 < r1; e += 4){
    int s0 = perm[e], s1 = perm[e+1], s2 = perm[e+2], s3 = perm[e+3];
    float w00 = expf(leaky(el[s0*2]   + er0, 0.2f) - mx0) * inv0;
    float w01 = expf(leaky(el[s0*2+1] + er1, 0.2f) - mx1) * inv1;
    float w10 = expf(leaky(el[s1*2]   + er0, 0.2f) - mx0) * inv0;
    float w11 = expf(leaky(el[s1*2+1] + er1, 0.2f) - mx1) * inv1;
    float w20 = expf(leaky(el[s2*2]   + er0, 0.2f) - mx0) * inv0;
    float w21 = expf(leaky(el[s2*2+1] + er1, 0.2f) - mx1) * inv1;
    float w30 = expf(leaky(el[s3*2]   + er0, 0.2f) - mx0) * inv0;
    float w31 = expf(leaky(el[s3*2+1] + er1, 0.2f) - mx1) * inv1;
    const unsigned short* h0 = HB + (size_t)s0 * (2*D);
    const unsigned short* h1 = HB + (size_t)s1 * (2*D);
    const unsigned short* h2 = HB + (size_t)s2 * (2*D);
    const unsigned short* h3 = HB + (size_t)s3 * (2*D);
    #pragma unroll
    for (int j = 0; j < ITER; j++){
      int base = j*256 + lane*4;
      bf16x4 v0 = *(const bf16x4*)(h0 + base);
      bf16x4 v1 = *(const bf16x4*)(h1 + base);
      bf16x4 v2 = *(const bf16x4*)(h2 + base);
      bf16x4 v3 = *(const bf16x4*)(h3 + base);
      float a0 = (base < D) ? w00 : w01;
      float a1 = (base < D) ? w10 : w11;
      float a2 = (base < D) ? w20 : w21;
      float a3 = (base < D) ? w30 : w31;
      #pragma unroll
      for (int i = 0; i < 4; i++)
        acc[j][i] += a0 * bf2f((unsigned short)v0[i]) + a1 * bf2f((unsigned short)v1[i])
                   + a2 * bf2f((unsigned short)v2[i]) + a3 * bf2f((unsigned short)v3[i]);
    }
  }
  for (; e < r1; ++e){
    int s = perm[e];
    float a0 = expf(leaky(el[s*2]   + er0, 0.2f) - mx0) * inv0;
    float a1 = expf(leaky(el[s*2+1] + er1, 0.2f) - mx1) * inv1;
    const unsigned short* hrow = HB + (size_t)s * (2*D);
    #pragma unroll
    for (int j = 0; j < ITER; j++){
      int base = j*256 + lane*4;
      bf16x4 v = *(const bf16x4*)(hrow + base);
      float a = (base < D) ? a0 : a1;
      #pragma unroll
      for (int i = 0; i < 4; i++)
        acc[j][i] += a * bf2f((unsigned short)v[i]);
    }
  }
  unsigned short* rrow = RB + (size_t)n * (2*D);
  #pragma unroll
  for (int j = 0; j < ITER; j++){
    int base = j*256 + lane*4;
    bf16x4 r = *(bf16x4*)(rrow + base);
    ushort4 o;
    o.x = f2bf(bf2f((unsigned short)r[0]) + acc[j][0]);
    o.y = f2bf(bf2f((unsigned short)r[1]) + acc[j][1]);
    o.z = f2bf(bf2f((unsigned short)r[2]) + acc[j][2]);
    o.w = f2bf(bf2f((unsigned short)r[3]) + acc[j][3]);
    *(ushort4*)(rrow + base) = o;
  }
}

// ------- GraphNorm stats (bf16 in): grid (NNODES/128, nn/256); lane owns 4 cols -------
__global__ __launch_bounds__(256) void k_stats(const unsigned short* __restrict__ R, int nn,
                                               float* __restrict__ gsum, float* __restrict__ gsq){
  int t = threadIdx.x, lane = t & 63, w = t >> 6;
  int c = blockIdx.y * 256 + lane * 4;
  const unsigned short* base = R + (size_t)(blockIdx.x * 128 + w) * nn + c;
  float4 s = make_float4(0,0,0,0), q = make_float4(0,0,0,0);
  #pragma unroll 4
  for (int i = 0; i < 32; i++){
    bf16x4 bv = *(const bf16x4*)(base + (size_t)(i * 4) * nn);
    float vx = bf2f((unsigned short)bv[0]), vy = bf2f((unsigned short)bv[1]);
    float vz = bf2f((unsigned short)bv[2]), vw = bf2f((unsigned short)bv[3]);
    s.x += vx; s.y += vy; s.z += vz; s.w += vw;
    q.x += vx*vx; q.y += vy*vy; q.z += vz*vz; q.w += vw*vw;
  }
  __shared__ float4 rs[256], rq[256];
  rs[t] = s; rq[t] = q; __syncthreads();
  if (t < 64){
    float4 a = rs[t], b = rs[t+64], c2 = rs[t+128], d2 = rs[t+192];
    float4 e = rq[t], f = rq[t+64], g2 = rq[t+128], h2 = rq[t+192];
    int cc = blockIdx.y * 256 + t * 4;
    atomicAdd(&gsum[cc+0], a.x+b.x+c2.x+d2.x);
    atomicAdd(&gsum[cc+1], a.y+b.y+c2.y+d2.y);
    atomicAdd(&gsum[cc+2], a.z+b.z+c2.z+d2.z);
    atomicAdd(&gsum[cc+3], a.w+b.w+c2.w+d2.w);
    atomicAdd(&gsq [cc+0], e.x+f.x+g2.x+h2.x);
    atomicAdd(&gsq [cc+1], e.y+f.y+g2.y+h2.y);
    atomicAdd(&gsq [cc+2], e.z+f.z+g2.z+h2.z);
    atomicAdd(&gsq [cc+3], e.w+f.w+g2.w+h2.w);
  }
}

// -- norm apply + leaky + head-mean pool (bf16 in) with INLINE stats finalize --
// grid (NNODES/128, nn/256); params are d-length; column c -> channel c & (d-1).
__global__ __launch_bounds__(256) void k_norm_pool(const unsigned short* __restrict__ R,
                                                   unsigned short* __restrict__ Xn, // bf16 next-layer input (or null)
                                                   const float* __restrict__ gsum,
                                                   const float* __restrict__ gsq,
                                                   const float* __restrict__ gamma,
                                                   const float* __restrict__ beta,
                                                   const float* __restrict__ alpha,
                                                   float* __restrict__ pool, int d, int loff){
  int t = threadIdx.x, lane = t & 63, w = t >> 6;
  int c = blockIdx.y * 256 + lane * 4;
  int cm = c & (d - 1);                    // channel index (d-periodic), 4-aligned
  int nodeb = blockIdx.x * 128;
  int g = blockIdx.x >> 3;                 // 8 row-blocks per graph (1024 nodes/graph)
  int nn = 2 * d;
  const float Minv = 1.0f / (2.0f * (float)NNODES);
  float4 gg = *(const float4*)(gamma + cm);
  float4 bb = *(const float4*)(beta + cm);
  float4 aa = *(const float4*)(alpha + cm);
  float mmv[4], rrv[4];
  #pragma unroll
  for (int i = 0; i < 4; i++){
    float m = (gsum[cm+i] + gsum[cm+i+d]) * Minv;
    float q = (gsq [cm+i] + gsq [cm+i+d]) * Minv;
    float a = (i==0)?aa.x:(i==1)?aa.y:(i==2)?aa.z:aa.w;
    float var = q - a * m * m * (2.0f - a);
    mmv[i] = m; rrv[i] = rsqrtf(var + 1e-5f);
  }
  float am0 = aa.x*mmv[0], am1 = aa.y*mmv[1], am2 = aa.z*mmv[2], am3 = aa.w*mmv[3];
  const unsigned short* base = R + (size_t)(nodeb + w) * nn + c;
  unsigned short* xb = Xn ? (Xn + (size_t)(nodeb + w) * nn + c) : nullptr;
  float4 accp = make_float4(0,0,0,0);
  #pragma unroll 4
  for (int i = 0; i < 32; i++){
    bf16x4 bv = *(const bf16x4*)(base + (size_t)(i * 4) * nn);
    float vx = bf2f((unsigned short)bv[0]), vy = bf2f((unsigned short)bv[1]);
    float vz = bf2f((unsigned short)bv[2]), vw = bf2f((unsigned short)bv[3]);
    float y0 = gg.x*(vx-am0)*rrv[0] + bb.x; y0 = y0 >= 0.f ? y0 : 0.01f*y0;
    float y1 = gg.y*(vy-am1)*rrv[1] + bb.y; y1 = y1 >= 0.f ? y1 : 0.01f*y1;
    float y2 = gg.z*(vz-am2)*rrv[2] + bb.z; y2 = y2 >= 0.f ? y2 : 0.01f*y2;
    float y3 = gg.w*(vw-am3)*rrv[3] + bb.w; y3 = y3 >= 0.f ? y3 : 0.01f*y3;
    if (xb){
      ushort4 o; o.x = f2bf(y0); o.y = f2bf(y1); o.z = f2bf(y2); o.w = f2bf(y3);
      *(ushort4*)(xb + (size_t)(i * 4) * nn) = o;
    }
    accp.x += y0; accp.y += y1; accp.z += y2; accp.w += y3;
  }
  __shared__ float4 red[256];
  red[t] = accp; __syncthreads();
  if (t < 64){
    float4 a = red[t], b = red[t+64], c2 = red[t+128], d2 = red[t+192];
    int cc = blockIdx.y * 256 + t * 4;
    float* pb = pool + g * 896 + loff;
    atomicAdd(&pb[(cc+0) & (d-1)], 0.5f*(a.x+b.x+c2.x+d2.x));
    atomicAdd(&pb[(cc+1) & (d-1)], 0.5f*(a.y+b.y+c2.y+d2.y));
    atomicAdd(&pb[(cc+2) & (d-1)], 0.5f*(a.z+b.z+c2.z+d2.z));
    atomicAdd(&pb[(cc+3) & (d-1)], 0.5f*(a.w+b.w+c2.w+d2.w));
  }
}

__global__ void k_final(const float* __restrict__ pool, const float* __restrict__ counts,
                        float* __restrict__ out){
  int idx = blockIdx.x * 256 + threadIdx.x;
  if (idx >= NGRAPHS * 896) return;
  int g = idx / 896;
  float v = pool[idx] / counts[g];
  out[idx] = v >= 0.0f ? v : 0.01f * v;
}

// ---------------------------------------------------------------------------------------
extern "C" void kernel_launch(void* const* d_in, const int* in_sizes, int n_in,
                              void* d_out, int out_size, void* d_ws, size_t ws_size,
                              hipStream_t stream){
  const float* x0 = (const float*)d_in[0];
  const float *W[3], *AL[3], *AR[3], *RW[3], *GA[3], *BE[3], *ALP[3];
  for (int l = 0; l < 3; l++){
    const int b = 1 + l*7;
    W[l]  = (const float*)d_in[b+0];
    AL[l] = (const float*)d_in[b+1];
    AR[l] = (const float*)d_in[b+2];
    RW[l] = (const float*)d_in[b+3];
    GA[l] = (const float*)d_in[b+4];
    BE[l] = (const float*)d_in[b+5];
    ALP[l]= (const float*)d_in[b+6];
  }
  const int* esrc = (const int*)d_in[22];
  const int* edst = (const int*)d_in[23];
  const int* gid  = (const int*)d_in[24];
  float* out = (float*)d_out;

  char* p = (char*)d_ws;
  auto carve = [&](size_t bytes)->void*{
    void* r = (void*)p; p += (bytes + 255) & ~(size_t)255; return r;
  };
  unsigned short* HB = (unsigned short*)carve((size_t)NNODES * 1024 * 2);  // h bf16 [N, 2d]
  unsigned short* RB = (unsigned short*)carve((size_t)NNODES * 1024 * 2);  // r/out bf16 [N, 2d]
  unsigned short* X0b = (unsigned short*)carve((size_t)NNODES * 128 * 2);  // bf16 layer-0 input
  unsigned short* XA  = (unsigned short*)carve((size_t)NNODES * 256 * 2);  // bf16 y0
  unsigned short* XB  = (unsigned short*)carve((size_t)NNODES * 512 * 2);  // bf16 y1
  unsigned short* Wt  = (unsigned short*)carve((size_t)1024 * 512 * 2);    // bf16 W^T (max)
  unsigned short* RWt = (unsigned short*)carve((size_t)1024 * 512 * 2);    // bf16 resW^T (max)
  float* el     = (float*)carve((size_t)NNODES * 2 * 4);
  float* er     = (float*)carve((size_t)NNODES * 2 * 4);
  float* elp    = (float*)carve((size_t)NNODES * 16 * 4);    // el partials (G<=16)
  float* erp    = (float*)carve((size_t)NNODES * 16 * 4);    // er partials
  int*   deg    = (int*)  carve((size_t)NNODES * 4);
  int*   rowptr = (int*)  carve((size_t)(NNODES + 1) * 4);
  int*   cursor = (int*)  carve((size_t)NNODES * 4);
  int*   perm   = (int*)  carve((size_t)NEDGES * 4);
  float* stats  = (float*)carve(3 * 2048 * 4);               // per-layer gsum|gsq arenas
  float* pool   = (float*)carve((size_t)NGRAPHS * 896 * 4);
  float* countsF= (float*)carve((size_t)NGRAPHS * 4);
  (void)ws_size; (void)in_sizes; (void)n_in; (void)out_size;

  hipMemsetAsync(deg, 0, NNODES * 4, stream);
  hipMemsetAsync(pool, 0, NGRAPHS * 896 * 4, stream);
  hipMemsetAsync(countsF, 0, NGRAPHS * 4, stream);
  hipMemsetAsync(stats, 0, 3 * 2048 * 4, stream);

  k_deg    <<<NEDGES/256, 256, 0, stream>>>(edst, deg);
  k_scan   <<<1, 1024, 0, stream>>>(deg, rowptr, cursor);
  k_scatter<<<NEDGES/256, 256, 0, stream>>>(esrc, edst, cursor, perm);
  k_counts <<<NNODES/1024, 256, 0, stream>>>(gid, countsF);
  k_cvt    <<<(NNODES*128/4 + 255)/256, 256, 0, stream>>>(x0, X0b, NNODES*128/4);

  const unsigned short* xin = X0b;
  int loff = 0;
  const int dims[3] = {128, 256, 512};
  for (int l = 0; l < 3; l++){
    int d = dims[l], nn = 2*d;
    float* gsum = stats + l * 2048;
    float* gsq  = gsum + 1024;
    dim3 gt(nn/32, d/32, 2);
    k_cvt_t2<<<gt, 256, 0, stream>>>(W[l], RW[l], Wt, RWt, d, nn);
    dim3 gg(2*nn/128, NNODES/128);
    k_gemm2<<<gg, 256, 0, stream>>>(xin, Wt, RWt, HB, RB, AL[l], AR[l], elp, erp, d, nn);
    k_elred<<<NNODES/256, 256, 0, stream>>>(elp, erp, el, er, nn >> 6);
    if (d == 128){
      k_attn<128><<<NNODES/4, 256, 0, stream>>>(HB, RB, el, er, rowptr, perm);
    } else if (d == 256){
      k_attn<256><<<NNODES/4, 256, 0, stream>>>(HB, RB, el, er, rowptr, perm);
    } else {
      k_attn<512><<<NNODES/4, 256, 0, stream>>>(HB, RB, el, er, rowptr, perm);
    }
    dim3 gs(NNODES/128, nn/256);
    k_stats   <<<gs, 256, 0, stream>>>(RB, nn, gsum, gsq);
    unsigned short* xn = (l == 0) ? XA : (l == 1) ? XB : nullptr;
    k_norm_pool<<<gs, 256, 0, stream>>>(RB, xn, gsum, gsq, GA[l], BE[l], ALP[l], pool, d, loff);
    xin = xn; loff += d;
  }
  k_final<<<(NGRAPHS*896 + 255)/256, 256, 0, stream>>>(pool, countsF, out);
}